// Round 15
// baseline (1288.582 us; speedup 1.0000x reference)
//
#include <hip/hip_runtime.h>
#include <math.h>

#define N_NODES 50000
#define N_EDGES 800000
#define D 128
#define AVG_D_LOG 2.833213344056216f  /* log(17.0) */
#define EPS 1e-5f

// DIAGNOSTIC ROUND: replicate heavy kernels so each dispatch exceeds the
// ~240us fillBuffer floor and surfaces in rocprof top-5 with counters.
// Replica blocks write byte-identical values to identical addresses (race-free).
#define REP_EDGE 3
#define REP_AGG  4
#define REP_POST 4

typedef __attribute__((ext_vector_type(8))) short bf16x8;
typedef __attribute__((ext_vector_type(4))) float f32x4;

__device__ __forceinline__ unsigned short f2bf(float x) {
    unsigned u = __float_as_uint(x);
    u += 0x7fffu + ((u >> 16) & 1u);
    return (unsigned short)(u >> 16);
}
__device__ __forceinline__ unsigned pk2bf(float a, float b) {
    return (unsigned)f2bf(a) | ((unsigned)f2bf(b) << 16);
}
__device__ __forceinline__ float bf2f(unsigned short u) {
    return __uint_as_float(((unsigned)u) << 16);
}

// ---------------- init (fallback only) ----------------
__global__ void k_init(int* hist, float* s1, float* s2, float* mx, float* mn) {
    size_t stride = (size_t)gridDim.x * blockDim.x;
    size_t i0 = (size_t)blockIdx.x * blockDim.x + threadIdx.x;
    const size_t ND4 = (size_t)N_NODES * D / 4;
    float4 z4 = {0.f, 0.f, 0.f, 0.f};
    int4 inf4 = {0x7f800000, 0x7f800000, 0x7f800000, 0x7f800000};
    for (size_t t = i0; t < ND4; t += stride) {
        ((float4*)s1)[t] = z4; ((float4*)s2)[t] = z4; ((float4*)mx)[t] = z4;
        ((int4*)mn)[t] = inf4;
    }
    for (size_t t = i0; t < N_NODES; t += stride) hist[t] = 0;
}

// ---------------- fused prep: 3 weight transposes + dst histogram ----------------
__global__ void k_prep(const float* __restrict__ wp, const float* __restrict__ w1,
                       const float* __restrict__ w2,
                       unsigned short* __restrict__ wpT, unsigned short* __restrict__ w1T,
                       unsigned short* __restrict__ w2T,
                       const int* __restrict__ dst, int* hist) {
    int b = blockIdx.x, t = threadIdx.x;
    if (b < 192) {
        int idx = b * 256 + t;
        int k = idx >> 7, c = idx & 127;
        wpT[(size_t)c * 384 + k] = f2bf(wp[idx]);
    } else if (b < 1024) {
        int idx = (b - 192) * 256 + t;
        int k = idx >> 7, c = idx & 127;
        w1T[(size_t)c * 1664 + k] = f2bf(w1[idx]);
    } else if (b < 1088) {
        int idx = (b - 1024) * 256 + t;
        int k = idx >> 7, c = idx & 127;
        w2T[(size_t)c * 128 + k] = f2bf(w2[idx]);
    } else {
        int e = (b - 1088) * 256 + t;
        if (e < N_EDGES) atomicAdd(&hist[dst[e]], 1);
    }
}

// ---------------- parallel exclusive scan ----------------
__global__ __launch_bounds__(1024) void k_scan(const int* __restrict__ hist, int* cursor) {
    __shared__ int part[1024];
    int t = threadIdx.x;
    const int chunk = (N_NODES + 1023) / 1024;
    int lo = t * chunk;
    int hi = lo + chunk; if (hi > N_NODES) hi = N_NODES;
    int s = 0;
    for (int i = lo; i < hi; ++i) s += hist[i];
    part[t] = s;
    __syncthreads();
    for (int off = 1; off < 1024; off <<= 1) {
        int v = (t >= off) ? part[t - off] : 0;
        __syncthreads();
        part[t] += v;
        __syncthreads();
    }
    int run = (t == 0) ? 0 : part[t - 1];
    for (int i = lo; i < hi; ++i) { cursor[i] = run; run += hist[i]; }
}

__global__ void k_scatter(const int* __restrict__ dst, int* cursor, int* perm) {
    int e = blockIdx.x * blockDim.x + threadIdx.x;
    if (e < N_EDGES) {
        int pos = atomicAdd(&cursor[dst[e]], 1);
        perm[pos] = e;
    }
}

// ---- 256B-row-stride MFMA macro ----
#define MM256(ACC, AOFF, BOFF) do { \
    _Pragma("unroll") \
    for (int ks = 0; ks < 4; ++ks) { \
        bf16x8 afr[2], bfr[4]; \
        int kb = ks * 64 + lg * 16; \
        _Pragma("unroll") \
        for (int cf = 0; cf < 2; ++cf) { \
            int c = w * 32 + cf * 16 + lr; \
            afr[cf] = *(const bf16x8*)(smem + (AOFF) + c * 256 + (kb ^ ((c & 7) << 4))); \
        } \
        _Pragma("unroll") \
        for (int eb = 0; eb < 4; ++eb) { \
            int e = eb * 16 + lr; \
            bfr[eb] = *(const bf16x8*)(smem + (BOFF) + e * 256 + (kb ^ ((e & 7) << 4))); \
        } \
        _Pragma("unroll") \
        for (int cf = 0; cf < 2; ++cf) \
            _Pragma("unroll") \
            for (int eb = 0; eb < 4; ++eb) \
                ACC[cf][eb] = __builtin_amdgcn_mfma_f32_16x16x32_bf16( \
                    afr[cf], bfr[eb], ACC[cf][eb], 0, 0, 0); \
    } \
} while (0)

// ---------------- k_node: P1 = nf@Ws, P2 = nf@Wd + b (bf16 out) ----------------
__global__ __launch_bounds__(256) void k_node(
    const float* __restrict__ nf, const unsigned short* __restrict__ wpT,
    const float* __restrict__ bp,
    unsigned short* __restrict__ p1, unsigned short* __restrict__ p2)
{
    __shared__ __align__(16) char smem[49152];
    __shared__ float sb[128];
    int t = threadIdx.x;
    int n0 = blockIdx.x * 64;
    if (t < 128) sb[t] = bp[t];
    int w = t >> 6, l = t & 63, lr = l & 15, lg = l >> 4;

    f32x4 acc1[2][4], acc2[2][4];
    #pragma unroll
    for (int i = 0; i < 2; ++i)
        #pragma unroll
        for (int j = 0; j < 4; ++j) { acc1[i][j] = (f32x4){0.f,0.f,0.f,0.f}; acc2[i][j] = (f32x4){0.f,0.f,0.f,0.f}; }

    #pragma unroll
    for (int p = 0; p < 8; ++p) {
        int g = t + 256 * p;
        int e = g >> 5, q = g & 31;
        int n = n0 + e;
        float4 fv = {0.f, 0.f, 0.f, 0.f};
        if (n < N_NODES) fv = *(const float4*)(nf + (size_t)n * D + q * 4);
        uint2 hv = { pk2bf(fv.x, fv.y), pk2bf(fv.z, fv.w) };
        *(uint2*)(smem + 32768 + e * 256 + ((q * 8) ^ ((e & 7) << 4))) = hv;
    }
    #pragma unroll
    for (int p = 0; p < 8; ++p) {
        int g = t + 256 * p;
        int c = g >> 4, j = g & 15;
        uint4 wv = *(const uint4*)(wpT + (size_t)c * 384 + j * 8);
        *(uint4*)(smem + c * 256 + ((j * 16) ^ ((c & 7) << 4))) = wv;
    }
    __syncthreads();
    MM256(acc1, 0, 32768);
    __syncthreads();
    #pragma unroll
    for (int p = 0; p < 8; ++p) {
        int g = t + 256 * p;
        int c = g >> 4, j = g & 15;
        uint4 wv = *(const uint4*)(wpT + (size_t)c * 384 + 128 + j * 8);
        *(uint4*)(smem + c * 256 + ((j * 16) ^ ((c & 7) << 4))) = wv;
    }
    __syncthreads();
    MM256(acc2, 0, 32768);
    __syncthreads();

    #pragma unroll
    for (int cf = 0; cf < 2; ++cf)
        #pragma unroll
        for (int eb = 0; eb < 4; ++eb) {
            int e  = eb * 16 + lr;
            int c0 = w * 32 + cf * 16 + lg * 4;
            uint2 v1 = { pk2bf(acc1[cf][eb][0], acc1[cf][eb][1]),
                         pk2bf(acc1[cf][eb][2], acc1[cf][eb][3]) };
            *(uint2*)(smem + e * 256 + ((c0 * 2) ^ ((e & 7) << 4))) = v1;
            uint2 v2 = { pk2bf(acc2[cf][eb][0] + sb[c0 + 0], acc2[cf][eb][1] + sb[c0 + 1]),
                         pk2bf(acc2[cf][eb][2] + sb[c0 + 2], acc2[cf][eb][3] + sb[c0 + 3]) };
            *(uint2*)(smem + 16384 + e * 256 + ((c0 * 2) ^ ((e & 7) << 4))) = v2;
        }
    __syncthreads();
    #pragma unroll
    for (int p = 0; p < 4; ++p) {
        int e = (t >> 4) + p * 16;
        int q = t & 15;
        int n = n0 + e;
        if (n < N_NODES) {
            int qq = q ^ (e & 7);
            uint4 v1 = *(const uint4*)(smem + e * 256 + q * 16);
            *(uint4*)(p1 + (size_t)n * D + qq * 8) = v1;
            uint4 v2 = *(const uint4*)(smem + 16384 + e * 256 + q * 16);
            *(uint4*)(p2 + (size_t)n * D + qq * 8) = v2;
        }
    }
}

// ---------------- k_edge (REPLICATED x REP_EDGE for diagnostics) ----------------
__global__ __launch_bounds__(256) void k_edge(
    const float* __restrict__ ef, const unsigned short* __restrict__ wpT,
    const int* __restrict__ src, const int* __restrict__ dst,
    const unsigned short* __restrict__ p1, const unsigned short* __restrict__ p2,
    unsigned short* __restrict__ msgG)
{
    __shared__ __align__(16) char smem[49152];
    __shared__ int sidx[64], didx[64];

    int t = threadIdx.x;
    int e0 = (blockIdx.x % (N_EDGES / 64)) * 64;   // replica blocks redo identical work
    if (t < 64) { sidx[t] = src[e0 + t]; didx[t] = dst[e0 + t]; }
    int w = t >> 6, l = t & 63, lr = l & 15, lg = l >> 4;

    f32x4 acc[2][4];
    #pragma unroll
    for (int i = 0; i < 2; ++i)
        #pragma unroll
        for (int j = 0; j < 4; ++j) acc[i][j] = (f32x4){0.f, 0.f, 0.f, 0.f};

    #pragma unroll
    for (int p = 0; p < 8; ++p) {
        int g = t + 256 * p;
        int c = g >> 4, j = g & 15;
        uint4 wv = *(const uint4*)(wpT + (size_t)c * 384 + 256 + j * 8);
        *(uint4*)(smem + c * 256 + ((j * 16) ^ ((c & 7) << 4))) = wv;
    }
    #pragma unroll
    for (int p = 0; p < 8; ++p) {
        int g = t + 256 * p;
        int e = g >> 5, q = g & 31;
        float4 fv = *(const float4*)(ef + (size_t)(e0 + e) * D + q * 4);
        uint2 hv = { pk2bf(fv.x, fv.y), pk2bf(fv.z, fv.w) };
        *(uint2*)(smem + 32768 + e * 256 + ((q * 8) ^ ((e & 7) << 4))) = hv;
    }
    __syncthreads();
    MM256(acc, 0, 32768);
    __syncthreads();
    #pragma unroll
    for (int p = 0; p < 4; ++p) {
        int g = t + 256 * p;
        int e = g >> 4, q = g & 15;
        uint4 v1 = *(const uint4*)(p1 + (size_t)sidx[e] * D + q * 8);
        *(uint4*)(smem + e * 256 + ((q * 16) ^ ((e & 7) << 4))) = v1;
        uint4 v2 = *(const uint4*)(p2 + (size_t)didx[e] * D + q * 8);
        *(uint4*)(smem + 16384 + e * 256 + ((q * 16) ^ ((e & 7) << 4))) = v2;
    }
    __syncthreads();
    #pragma unroll
    for (int cf = 0; cf < 2; ++cf)
        #pragma unroll
        for (int eb = 0; eb < 4; ++eb) {
            int e  = eb * 16 + lr;
            int c0 = w * 32 + cf * 16 + lg * 4;
            uint2 a1 = *(const uint2*)(smem + e * 256 + ((c0 * 2) ^ ((e & 7) << 4)));
            uint2 a2 = *(const uint2*)(smem + 16384 + e * 256 + ((c0 * 2) ^ ((e & 7) << 4)));
            float v0 = acc[cf][eb][0] + bf2f((unsigned short)(a1.x & 0xffff)) + bf2f((unsigned short)(a2.x & 0xffff));
            float v1 = acc[cf][eb][1] + bf2f((unsigned short)(a1.x >> 16))    + bf2f((unsigned short)(a2.x >> 16));
            float v2 = acc[cf][eb][2] + bf2f((unsigned short)(a1.y & 0xffff)) + bf2f((unsigned short)(a2.y & 0xffff));
            float v3 = acc[cf][eb][3] + bf2f((unsigned short)(a1.y >> 16))    + bf2f((unsigned short)(a2.y >> 16));
            uint2 mv = { pk2bf(fmaxf(v0, 0.f), fmaxf(v1, 0.f)),
                         pk2bf(fmaxf(v2, 0.f), fmaxf(v3, 0.f)) };
            *(uint2*)(smem + 32768 + e * 256 + ((c0 * 2) ^ ((e & 7) << 4))) = mv;
        }
    __syncthreads();
    #pragma unroll
    for (int p = 0; p < 4; ++p) {
        int e = (t >> 4) + p * 16;
        int q = t & 15;
        uint4 v = *(const uint4*)(smem + 32768 + e * 256 + q * 16);
        int qq = q ^ (e & 7);
        *(uint4*)(msgG + (size_t)(e0 + e) * D + qq * 8) = v;
    }
}

// ---------------- k_agg (REPLICATED x REP_AGG) ----------------
__global__ __launch_bounds__(256) void k_agg(
    const unsigned short* __restrict__ msgG,
    const int* __restrict__ cursor, const int* __restrict__ hist,
    const int* __restrict__ perm,
    float* __restrict__ s1, float* __restrict__ s2,
    float* __restrict__ mx, float* __restrict__ mn, float* __restrict__ scal)
{
    int t = threadIdx.x;
    int n = (blockIdx.x % (N_NODES / 4)) * 4 + (t >> 6);
    int tl = t & 63;
    int deg = hist[n];
    int re  = cursor[n];
    int rs  = re - deg;

    float sum0 = 0.f, sum1 = 0.f, sq0 = 0.f, sq1 = 0.f;
    float mx0 = -3.402823e38f, mx1 = -3.402823e38f;
    float mn0 =  3.402823e38f, mn1 =  3.402823e38f;
    const uint* mg = (const uint*)msgG;
    int pe_next = (deg > 0) ? perm[rs] : 0;
    for (int e = 0; e < deg; ++e) {
        int pe = pe_next;
        if (e + 1 < deg) pe_next = perm[rs + e + 1];
        uint v = mg[(size_t)pe * 64 + tl];
        float a = bf2f((unsigned short)(v & 0xffff));
        float b = bf2f((unsigned short)(v >> 16));
        sum0 += a; sum1 += b; sq0 += a * a; sq1 += b * b;
        mx0 = fmaxf(mx0, a); mx1 = fmaxf(mx1, b);
        mn0 = fminf(mn0, a); mn1 = fminf(mn1, b);
    }
    float dg = (float)deg;
    float ds = fmaxf(dg, 1.f);
    bool nb = deg > 0;
    float m0 = sum0 / ds, m1 = sum1 / ds;
    float sd0 = sqrtf(fmaxf(sq0 / ds - m0 * m0, 0.f) + EPS);
    float sd1 = sqrtf(fmaxf(sq1 / ds - m1 * m1, 0.f) + EPS);
    size_t base = (size_t)n * D + tl * 2;
    *(float2*)&s1[base] = (float2){m0, m1};
    *(float2*)&s2[base] = (float2){sd0, sd1};
    *(float2*)&mx[base] = (float2){nb ? mx0 : 0.f, nb ? mx1 : 0.f};
    *(float2*)&mn[base] = (float2){nb ? mn0 : 0.f, nb ? mn1 : 0.f};
    if (tl == 0) {
        float logd = logf(dg + 1.f);
        scal[2 * n]     = logd / AVG_D_LOG;
        scal[2 * n + 1] = AVG_D_LOG / fmaxf(logd, EPS);
    }
}

// staging macros for the fallback fused pretrans
#define PFN(NC, PW0, PW1, PW2, PW3, PZ0, PZ1, PZ2, PZ3) do { \
    { int g = t;       int c = g >> 3, j = g & 7;  PW0 = *(const uint4*)(wpT + (size_t)c * 384 + (NC) * 64 + j * 8); } \
    { int g = t + 256; int c = g >> 3, j = g & 7;  PW1 = *(const uint4*)(wpT + (size_t)c * 384 + (NC) * 64 + j * 8); } \
    { int g = t + 512; int c = g >> 3, j = g & 7;  PW2 = *(const uint4*)(wpT + (size_t)c * 384 + (NC) * 64 + j * 8); } \
    { int g = t + 768; int c = g >> 3, j = g & 7;  PW3 = *(const uint4*)(wpT + (size_t)c * 384 + (NC) * 64 + j * 8); } \
    { int g = t;       int e = g >> 4, q = g & 15; PZ0 = *(const float4*)(ZROW(NC, e) + (((NC) & 1) * 64) + q * 4); } \
    { int g = t + 256; int e = g >> 4, q = g & 15; PZ1 = *(const float4*)(ZROW(NC, e) + (((NC) & 1) * 64) + q * 4); } \
    { int g = t + 512; int e = g >> 4, q = g & 15; PZ2 = *(const float4*)(ZROW(NC, e) + (((NC) & 1) * 64) + q * 4); } \
    { int g = t + 768; int e = g >> 4, q = g & 15; PZ3 = *(const float4*)(ZROW(NC, e) + (((NC) & 1) * 64) + q * 4); } \
} while (0)
#define WRN(OFF, PW0, PW1, PW2, PW3, PZ0, PZ1, PZ2, PZ3) do { \
    { int g = t;       int c = g >> 3, j = g & 7;  *(uint4*)(smem + (OFF) + c * 128 + ((j * 16) ^ ((c & 7) << 4))) = PW0; } \
    { int g = t + 256; int c = g >> 3, j = g & 7;  *(uint4*)(smem + (OFF) + c * 128 + ((j * 16) ^ ((c & 7) << 4))) = PW1; } \
    { int g = t + 512; int c = g >> 3, j = g & 7;  *(uint4*)(smem + (OFF) + c * 128 + ((j * 16) ^ ((c & 7) << 4))) = PW2; } \
    { int g = t + 768; int c = g >> 3, j = g & 7;  *(uint4*)(smem + (OFF) + c * 128 + ((j * 16) ^ ((c & 7) << 4))) = PW3; } \
    { int g = t;       int e = g >> 4, q = g & 15; uint2 hv = { pk2bf(PZ0.x, PZ0.y), pk2bf(PZ0.z, PZ0.w) }; \
      *(uint2*)(smem + (OFF) + 16384 + e * 128 + ((q * 8) ^ ((e & 7) << 4))) = hv; } \
    { int g = t + 256; int e = g >> 4, q = g & 15; uint2 hv = { pk2bf(PZ1.x, PZ1.y), pk2bf(PZ1.z, PZ1.w) }; \
      *(uint2*)(smem + (OFF) + 16384 + e * 128 + ((q * 8) ^ ((e & 7) << 4))) = hv; } \
    { int g = t + 512; int e = g >> 4, q = g & 15; uint2 hv = { pk2bf(PZ2.x, PZ2.y), pk2bf(PZ2.z, PZ2.w) }; \
      *(uint2*)(smem + (OFF) + 16384 + e * 128 + ((q * 8) ^ ((e & 7) << 4))) = hv; } \
    { int g = t + 768; int e = g >> 4, q = g & 15; uint2 hv = { pk2bf(PZ3.x, PZ3.y), pk2bf(PZ3.z, PZ3.w) }; \
      *(uint2*)(smem + (OFF) + 16384 + e * 128 + ((q * 8) ^ ((e & 7) << 4))) = hv; } \
} while (0)
#define MMO(OFF) do { \
    _Pragma("unroll") \
    for (int ks = 0; ks < 2; ++ks) { \
        bf16x8 afr[2], bfr[4]; \
        int kb = ks * 64 + lg * 16; \
        _Pragma("unroll") \
        for (int cf = 0; cf < 2; ++cf) { \
            int c = w * 32 + cf * 16 + lr; \
            afr[cf] = *(const bf16x8*)(smem + (OFF) + c * 128 + (kb ^ ((c & 7) << 4))); \
        } \
        _Pragma("unroll") \
        for (int eb = 0; eb < 4; ++eb) { \
            int e = eb * 16 + lr; \
            bfr[eb] = *(const bf16x8*)(smem + (OFF) + 16384 + e * 128 + (kb ^ ((e & 7) << 4))); \
        } \
        _Pragma("unroll") \
        for (int cf = 0; cf < 2; ++cf) \
            _Pragma("unroll") \
            for (int eb = 0; eb < 4; ++eb) \
                acc[cf][eb] = __builtin_amdgcn_mfma_f32_16x16x32_bf16( \
                    afr[cf], bfr[eb], acc[cf][eb], 0, 0, 0); \
    } \
} while (0)

// ---------------- fallback: fused pretrans (all-atomic epilogue) ----------------
__global__ __launch_bounds__(256) void k_pretrans(
    const float* __restrict__ nf, const float* __restrict__ ef,
    const unsigned short* __restrict__ wpT, const float* __restrict__ bp,
    const int* __restrict__ src, const int* __restrict__ dst,
    const int* __restrict__ perm,
    float* s1, float* s2, float* mx, float* mn)
{
    __shared__ __align__(16) char smem[24576];
    __shared__ int pidx[64], sidx[64], didx[64];
    __shared__ int seg_start[65], seg_dst[64];
    __shared__ int nseg_s;
    __shared__ float sb[128];

    int t = threadIdx.x;
    int e0 = blockIdx.x * 64;
    if (t < 64) {
        int pe = perm[e0 + t];
        pidx[t] = pe; sidx[t] = src[pe]; didx[t] = dst[pe];
    }
    if (t < 128) sb[t] = bp[t];
    __syncthreads();

    int w  = t >> 6;
    int l  = t & 63;
    int lr = l & 15;
    int lg = l >> 4;

    f32x4 acc[2][4];
    #pragma unroll
    for (int i = 0; i < 2; ++i)
        #pragma unroll
        for (int j = 0; j < 4; ++j) acc[i][j] = (f32x4){0.f, 0.f, 0.f, 0.f};

    uint4  pw0, pw1, pw2, pw3;
    float4 pz0, pz1, pz2, pz3;

#define ZROW(NC, e) ((NC) < 2 ? nf + (size_t)sidx[e] * D : \
                     (NC) < 4 ? nf + (size_t)didx[e] * D : \
                                ef + (size_t)pidx[e] * D)
    PFN(0, pw0, pw1, pw2, pw3, pz0, pz1, pz2, pz3);
    WRN(0, pw0, pw1, pw2, pw3, pz0, pz1, pz2, pz3); PFN(1, pw0, pw1, pw2, pw3, pz0, pz1, pz2, pz3); __syncthreads(); MMO(0); __syncthreads();
    WRN(0, pw0, pw1, pw2, pw3, pz0, pz1, pz2, pz3); PFN(2, pw0, pw1, pw2, pw3, pz0, pz1, pz2, pz3); __syncthreads(); MMO(0); __syncthreads();
    WRN(0, pw0, pw1, pw2, pw3, pz0, pz1, pz2, pz3); PFN(3, pw0, pw1, pw2, pw3, pz0, pz1, pz2, pz3); __syncthreads(); MMO(0); __syncthreads();
    WRN(0, pw0, pw1, pw2, pw3, pz0, pz1, pz2, pz3); PFN(4, pw0, pw1, pw2, pw3, pz0, pz1, pz2, pz3); __syncthreads(); MMO(0); __syncthreads();
    WRN(0, pw0, pw1, pw2, pw3, pz0, pz1, pz2, pz3); PFN(5, pw0, pw1, pw2, pw3, pz0, pz1, pz2, pz3); __syncthreads(); MMO(0); __syncthreads();
    WRN(0, pw0, pw1, pw2, pw3, pz0, pz1, pz2, pz3);                                                 __syncthreads(); MMO(0); __syncthreads();
#undef ZROW

    #pragma unroll
    for (int cf = 0; cf < 2; ++cf)
        #pragma unroll
        for (int eb = 0; eb < 4; ++eb) {
            int e  = eb * 16 + lr;
            int c0 = w * 32 + cf * 16 + lg * 4;
            float v0 = fmaxf(acc[cf][eb][0] + sb[c0 + 0], 0.f);
            float v1 = fmaxf(acc[cf][eb][1] + sb[c0 + 1], 0.f);
            float v2 = fmaxf(acc[cf][eb][2] + sb[c0 + 2], 0.f);
            float v3 = fmaxf(acc[cf][eb][3] + sb[c0 + 3], 0.f);
            uint2 mv = { pk2bf(v0, v1), pk2bf(v2, v3) };
            *(uint2*)(smem + e * 256 + ((c0 * 2) ^ ((e & 7) << 4))) = mv;
        }
    if (t == 0) {
        int ns = 0;
        for (int e = 0; e < 64; ++e) {
            if (e == 0 || didx[e] != didx[e - 1]) { seg_dst[ns] = didx[e]; seg_start[ns] = e; ++ns; }
        }
        seg_start[ns] = 64; nseg_s = ns;
    }
    __syncthreads();
    int nseg = nseg_s;
    for (int idx = t; idx < nseg * D; idx += 256) {
        int sg = idx >> 7, c = idx & 127;
        int eb2 = seg_start[sg], ee = seg_start[sg + 1];
        float s = 0.f, q = 0.f, vmax = 0.f, vmin = __int_as_float(0x7f800000);
        for (int e = eb2; e < ee; ++e) {
            float v = bf2f(*(const unsigned short*)(smem + e * 256 + ((c * 2) ^ ((e & 7) << 4))));
            s += v; q += v * v;
            vmax = fmaxf(vmax, v); vmin = fminf(vmin, v);
        }
        size_t base = (size_t)seg_dst[sg] * D + c;
        atomicAdd(&s1[base], s);
        atomicAdd(&s2[base], q);
        atomicMax((int*)&mx[base], __float_as_int(vmax));
        atomicMin((int*)&mn[base], __float_as_int(vmin));
    }
}

#undef PFN
#undef WRN
#undef MMO

// ---------------- fallback: finalize in place + scalers ----------------
__global__ void k_finalize(float* s1, float* s2, float* mx, float* mn,
                           const int* __restrict__ hist, float* scal) {
    size_t idx = (size_t)blockIdx.x * blockDim.x + threadIdx.x;
    if (idx >= (size_t)N_NODES * D) return;
    int n = (int)(idx >> 7);
    int c = (int)(idx & 127);
    float dg = (float)hist[n];
    float ds = fmaxf(dg, 1.f);
    float m  = s1[idx] / ds;
    float var = fmaxf(s2[idx] / ds - m * m, 0.f);
    float sd  = sqrtf(var + EPS);
    bool nb = dg > 0.f;
    s1[idx] = m;
    mx[idx] = nb ? mx[idx] : 0.f;
    mn[idx] = nb ? mn[idx] : 0.f;
    s2[idx] = sd;
    if (c == 0) {
        float logd = logf(dg + 1.f);
        scal[2 * n]     = logd / AVG_D_LOG;
        scal[2 * n + 1] = AVG_D_LOG / fmaxf(logd, EPS);
    }
}

// ---------------- fused posttrans (REPLICATED x REP_POST) ----------------
__global__ __launch_bounds__(256, 3) void k_post(
    const float* __restrict__ nf,
    const float* __restrict__ amean, const float* __restrict__ amax,
    const float* __restrict__ amin,  const float* __restrict__ astd,
    const float* __restrict__ scal,
    const unsigned short* __restrict__ w1T, const float* __restrict__ b1,
    const unsigned short* __restrict__ w2T, const float* __restrict__ b2,
    float* __restrict__ out)
{
    __shared__ __align__(16) char smem[49152];
    __shared__ float samp[64], satt[64], sb1[128], sb2[128];

    int t = threadIdx.x;
    int n0 = (blockIdx.x % ((N_NODES + 63) / 64)) * 64;
    if (t < 64) {
        int n = n0 + t;
        samp[t] = (n < N_NODES) ? scal[2 * n] : 0.f;
        satt[t] = (n < N_NODES) ? scal[2 * n + 1] : 0.f;
    }
    if (t < 128) { sb1[t] = b1[t]; sb2[t] = b2[t]; }
    __syncthreads();

    int w  = t >> 6, l = t & 63, lr = l & 15, lg = l >> 4;
    f32x4 acc[2][4];
    #pragma unroll
    for (int i = 0; i < 2; ++i)
        #pragma unroll
        for (int j = 0; j < 4; ++j) acc[i][j] = (f32x4){0.f, 0.f, 0.f, 0.f};

    for (int chunk = 0; chunk < 13; ++chunk) {
        #pragma unroll
        for (int p = 0; p < 8; ++p) {
            int g = t + 256 * p;
            int c = g >> 4, j = g & 15;
            uint4 wv = *(const uint4*)(w1T + (size_t)c * 1664 + chunk * 128 + j * 8);
            *(uint4*)(smem + c * 256 + ((j * 16) ^ ((c & 7) << 4))) = wv;
        }
        const float* base;
        int r;
        if (chunk == 0) { base = nf; r = 0; }
        else {
            int b = (chunk - 1) & 3;
            r = (chunk - 1) >> 2;
            base = (b == 0) ? amean : (b == 1) ? amax : (b == 2) ? amin : astd;
        }
        #pragma unroll
        for (int p = 0; p < 8; ++p) {
            int g = t + 256 * p;
            int e = g >> 5, q = g & 31;
            int n = n0 + e;
            float4 fv = {0.f, 0.f, 0.f, 0.f};
            if (n < N_NODES) {
                fv = *(const float4*)(base + (size_t)n * D + q * 4);
                if (r == 1) { float sc = samp[e]; fv.x *= sc; fv.y *= sc; fv.z *= sc; fv.w *= sc; }
                else if (r == 2) { float sc = satt[e]; fv.x *= sc; fv.y *= sc; fv.z *= sc; fv.w *= sc; }
            }
            uint2 hv = { pk2bf(fv.x, fv.y), pk2bf(fv.z, fv.w) };
            *(uint2*)(smem + 32768 + e * 256 + ((q * 8) ^ ((e & 7) << 4))) = hv;
        }
        __syncthreads();
        MM256(acc, 0, 32768);
        __syncthreads();
    }

    // h1 = relu(acc + b1) -> LDS B-layout @32768
    #pragma unroll
    for (int cf = 0; cf < 2; ++cf)
        #pragma unroll
        for (int eb = 0; eb < 4; ++eb) {
            int e  = eb * 16 + lr;
            int c0 = w * 32 + cf * 16 + lg * 4;
            float v0 = fmaxf(acc[cf][eb][0] + sb1[c0 + 0], 0.f);
            float v1 = fmaxf(acc[cf][eb][1] + sb1[c0 + 1], 0.f);
            float v2 = fmaxf(acc[cf][eb][2] + sb1[c0 + 2], 0.f);
            float v3 = fmaxf(acc[cf][eb][3] + sb1[c0 + 3], 0.f);
            uint2 hv = { pk2bf(v0, v1), pk2bf(v2, v3) };
            *(uint2*)(smem + 32768 + e * 256 + ((c0 * 2) ^ ((e & 7) << 4))) = hv;
        }
    #pragma unroll
    for (int p = 0; p < 8; ++p) {
        int g = t + 256 * p;
        int c = g >> 4, j = g & 15;
        uint4 wv = *(const uint4*)(w2T + (size_t)c * 128 + j * 8);
        *(uint4*)(smem + c * 256 + ((j * 16) ^ ((c & 7) << 4))) = wv;
    }
    __syncthreads();

    f32x4 acc2[2][4];
    #pragma unroll
    for (int i = 0; i < 2; ++i)
        #pragma unroll
        for (int j = 0; j < 4; ++j) acc2[i][j] = (f32x4){0.f, 0.f, 0.f, 0.f};
    MM256(acc2, 0, 32768);

    #pragma unroll
    for (int cf = 0; cf < 2; ++cf)
        #pragma unroll
        for (int eb = 0; eb < 4; ++eb) {
            int n = n0 + eb * 16 + lr;
            if (n < N_NODES) {
                int c0 = w * 32 + cf * 16 + lg * 4;
                float4 rv = *(const float4*)(nf + (size_t)n * D + c0);
                float4 ov = { acc2[cf][eb][0] + sb2[c0 + 0] + rv.x,
                              acc2[cf][eb][1] + sb2[c0 + 1] + rv.y,
                              acc2[cf][eb][2] + sb2[c0 + 2] + rv.z,
                              acc2[cf][eb][3] + sb2[c0 + 3] + rv.w };
                *(float4*)(out + (size_t)n * D + c0) = ov;
            }
        }
}

extern "C" void kernel_launch(void* const* d_in, const int* in_sizes, int n_in,
                              void* d_out, int out_size, void* d_ws, size_t ws_size,
                              hipStream_t stream) {
    const float* nf = (const float*)d_in[0];
    const float* ef = (const float*)d_in[1];
    const float* wp = (const float*)d_in[2];
    const float* bp = (const float*)d_in[3];
    const float* w1 = (const float*)d_in[4];
    const float* b1 = (const float*)d_in[5];
    const float* w2 = (const float*)d_in[6];
    const float* b2 = (const float*)d_in[7];
    const int* src  = (const int*)d_in[8];
    const int* dst  = (const int*)d_in[9];
    float* out = (float*)d_out;

    const size_t ND = (size_t)N_NODES * D;       // 6.4M
    const size_t MSG_SH = (size_t)N_EDGES * D;   // 102.4M ushorts
    char* wsb = (char*)d_ws;
    int*   hist   = (int*)wsb;                                   // 50048
    int*   cursor = hist + 50048;                                // 50048
    int*   perm   = cursor + 50048;                              // 800000
    unsigned short* wpT = (unsigned short*)(perm + N_EDGES);     // 49152
    unsigned short* w1T = wpT + 49152;                           // 212992
    unsigned short* w2T = w1T + 212992;                          // 16384
    unsigned short* tail = w2T + 16384;

    // CSR layout
    unsigned short* p1   = tail;                 // ND bf16
    unsigned short* p2   = p1 + ND;              // ND bf16
    unsigned short* msgG = p2 + ND;              // MSG_SH bf16
    float* s1   = (float*)(msgG + MSG_SH);
    float* s2   = s1 + ND;
    float* mx   = s2 + ND;
    float* mn   = mx + ND;
    float* scal = mn + ND;
    size_t need_csr = (size_t)((char*)(scal + 100096) - wsb);

    bool use_csr = ws_size >= need_csr;
    if (!use_csr) {
        s1   = (float*)tail;
        s2   = s1 + ND;
        mx   = s2 + ND;
        mn   = mx + ND;
        scal = mn + ND;
    }

    if (use_csr) {
        hipMemsetAsync(hist, 0, N_NODES * sizeof(int), stream);
    } else {
        hipLaunchKernelGGL(k_init, dim3(2048), dim3(256), 0, stream, hist, s1, s2, mx, mn);
    }
    hipLaunchKernelGGL(k_prep, dim3(1088 + (N_EDGES + 255) / 256), dim3(256), 0, stream,
                       wp, w1, w2, wpT, w1T, w2T, dst, hist);
    hipLaunchKernelGGL(k_scan, dim3(1), dim3(1024), 0, stream, hist, cursor);
    hipLaunchKernelGGL(k_scatter, dim3((N_EDGES + 255) / 256), dim3(256), 0, stream, dst, cursor, perm);
    if (use_csr) {
        hipLaunchKernelGGL(k_node, dim3((N_NODES + 63) / 64), dim3(256), 0, stream,
                           nf, wpT, bp, p1, p2);
        hipLaunchKernelGGL(k_edge, dim3(REP_EDGE * (N_EDGES / 64)), dim3(256), 0, stream,
                           ef, wpT, src, dst, p1, p2, msgG);
        hipLaunchKernelGGL(k_agg, dim3(REP_AGG * (N_NODES / 4)), dim3(256), 0, stream,
                           msgG, cursor, hist, perm, s1, s2, mx, mn, scal);
    } else {
        hipLaunchKernelGGL(k_pretrans, dim3(N_EDGES / 64), dim3(256), 0, stream,
                           nf, ef, wpT, bp, src, dst, perm, s1, s2, mx, mn);
        hipLaunchKernelGGL(k_finalize, dim3((unsigned)((ND + 255) / 256)), dim3(256), 0, stream,
                           s1, s2, mx, mn, hist, scal);
    }
    hipLaunchKernelGGL(k_post, dim3(REP_POST * ((N_NODES + 63) / 64)), dim3(256), 0, stream,
                       nf, s1, mx, mn, s2, scal, w1T, b1, w2T, b2, out);
}

// Round 16
// 586.429 us; speedup vs baseline: 2.1973x; 2.1973x over previous
//
#include <hip/hip_runtime.h>
#include <math.h>

#define N_NODES 50000
#define N_EDGES 800000
#define D 128
#define AVG_D_LOG 2.833213344056216f  /* log(17.0) */
#define EPS 1e-5f

typedef __attribute__((ext_vector_type(8))) short bf16x8;
typedef __attribute__((ext_vector_type(4))) float f32x4;

__device__ __forceinline__ unsigned short f2bf(float x) {
    unsigned u = __float_as_uint(x);
    u += 0x7fffu + ((u >> 16) & 1u);
    return (unsigned short)(u >> 16);
}
__device__ __forceinline__ unsigned pk2bf(float a, float b) {
    return (unsigned)f2bf(a) | ((unsigned)f2bf(b) << 16);
}
__device__ __forceinline__ float bf2f(unsigned short u) {
    return __uint_as_float(((unsigned)u) << 16);
}

// ---------------- init (fallback only) ----------------
__global__ void k_init(int* hist, float* s1, float* s2, float* mx, float* mn) {
    size_t stride = (size_t)gridDim.x * blockDim.x;
    size_t i0 = (size_t)blockIdx.x * blockDim.x + threadIdx.x;
    const size_t ND4 = (size_t)N_NODES * D / 4;
    float4 z4 = {0.f, 0.f, 0.f, 0.f};
    int4 inf4 = {0x7f800000, 0x7f800000, 0x7f800000, 0x7f800000};
    for (size_t t = i0; t < ND4; t += stride) {
        ((float4*)s1)[t] = z4; ((float4*)s2)[t] = z4; ((float4*)mx)[t] = z4;
        ((int4*)mn)[t] = inf4;
    }
    for (size_t t = i0; t < N_NODES; t += stride) hist[t] = 0;
}

// ---------------- fused prep: 3 weight transposes + dst histogram ----------------
__global__ void k_prep(const float* __restrict__ wp, const float* __restrict__ w1,
                       const float* __restrict__ w2,
                       unsigned short* __restrict__ wpT, unsigned short* __restrict__ w1T,
                       unsigned short* __restrict__ w2T,
                       const int* __restrict__ dst, int* hist) {
    int b = blockIdx.x, t = threadIdx.x;
    if (b < 192) {
        int idx = b * 256 + t;
        int k = idx >> 7, c = idx & 127;
        wpT[(size_t)c * 384 + k] = f2bf(wp[idx]);
    } else if (b < 1024) {
        int idx = (b - 192) * 256 + t;
        int k = idx >> 7, c = idx & 127;
        w1T[(size_t)c * 1664 + k] = f2bf(w1[idx]);
    } else if (b < 1088) {
        int idx = (b - 1024) * 256 + t;
        int k = idx >> 7, c = idx & 127;
        w2T[(size_t)c * 128 + k] = f2bf(w2[idx]);
    } else {
        int e = (b - 1088) * 256 + t;
        if (e < N_EDGES) atomicAdd(&hist[dst[e]], 1);
    }
}

// ---------------- parallel exclusive scan ----------------
__global__ __launch_bounds__(1024) void k_scan(const int* __restrict__ hist, int* cursor) {
    __shared__ int part[1024];
    int t = threadIdx.x;
    const int chunk = (N_NODES + 1023) / 1024;
    int lo = t * chunk;
    int hi = lo + chunk; if (hi > N_NODES) hi = N_NODES;
    int s = 0;
    for (int i = lo; i < hi; ++i) s += hist[i];
    part[t] = s;
    __syncthreads();
    for (int off = 1; off < 1024; off <<= 1) {
        int v = (t >= off) ? part[t - off] : 0;
        __syncthreads();
        part[t] += v;
        __syncthreads();
    }
    int run = (t == 0) ? 0 : part[t - 1];
    for (int i = lo; i < hi; ++i) { cursor[i] = run; run += hist[i]; }
}

__global__ void k_scatter(const int* __restrict__ dst, int* cursor, int* perm) {
    int e = blockIdx.x * blockDim.x + threadIdx.x;
    if (e < N_EDGES) {
        int pos = atomicAdd(&cursor[dst[e]], 1);
        perm[pos] = e;
    }
}

// ---- 256B-row-stride MFMA macro (K=128 tiles) ----
#define MM256(ACC, AOFF, BOFF) do { \
    _Pragma("unroll") \
    for (int ks = 0; ks < 4; ++ks) { \
        bf16x8 afr[2], bfr[4]; \
        int kb = ks * 64 + lg * 16; \
        _Pragma("unroll") \
        for (int cf = 0; cf < 2; ++cf) { \
            int c = w * 32 + cf * 16 + lr; \
            afr[cf] = *(const bf16x8*)(smem + (AOFF) + c * 256 + (kb ^ ((c & 7) << 4))); \
        } \
        _Pragma("unroll") \
        for (int eb = 0; eb < 4; ++eb) { \
            int e = eb * 16 + lr; \
            bfr[eb] = *(const bf16x8*)(smem + (BOFF) + e * 256 + (kb ^ ((e & 7) << 4))); \
        } \
        _Pragma("unroll") \
        for (int cf = 0; cf < 2; ++cf) \
            _Pragma("unroll") \
            for (int eb = 0; eb < 4; ++eb) \
                ACC[cf][eb] = __builtin_amdgcn_mfma_f32_16x16x32_bf16( \
                    afr[cf], bfr[eb], ACC[cf][eb], 0, 0, 0); \
    } \
} while (0)

// ---------------- k_node: P1 = nf@Ws, P2 = nf@Wd + b (bf16 out) ----------------
__global__ __launch_bounds__(256) void k_node(
    const float* __restrict__ nf, const unsigned short* __restrict__ wpT,
    const float* __restrict__ bp,
    unsigned short* __restrict__ p1, unsigned short* __restrict__ p2)
{
    __shared__ __align__(16) char smem[49152];
    __shared__ float sb[128];
    int t = threadIdx.x;
    int n0 = blockIdx.x * 64;
    if (t < 128) sb[t] = bp[t];
    int w = t >> 6, l = t & 63, lr = l & 15, lg = l >> 4;

    f32x4 acc1[2][4], acc2[2][4];
    #pragma unroll
    for (int i = 0; i < 2; ++i)
        #pragma unroll
        for (int j = 0; j < 4; ++j) { acc1[i][j] = (f32x4){0.f,0.f,0.f,0.f}; acc2[i][j] = (f32x4){0.f,0.f,0.f,0.f}; }

    #pragma unroll
    for (int p = 0; p < 8; ++p) {
        int g = t + 256 * p;
        int e = g >> 5, q = g & 31;
        int n = n0 + e;
        float4 fv = {0.f, 0.f, 0.f, 0.f};
        if (n < N_NODES) fv = *(const float4*)(nf + (size_t)n * D + q * 4);
        uint2 hv = { pk2bf(fv.x, fv.y), pk2bf(fv.z, fv.w) };
        *(uint2*)(smem + 32768 + e * 256 + ((q * 8) ^ ((e & 7) << 4))) = hv;
    }
    #pragma unroll
    for (int p = 0; p < 8; ++p) {
        int g = t + 256 * p;
        int c = g >> 4, j = g & 15;
        uint4 wv = *(const uint4*)(wpT + (size_t)c * 384 + j * 8);
        *(uint4*)(smem + c * 256 + ((j * 16) ^ ((c & 7) << 4))) = wv;
    }
    __syncthreads();
    MM256(acc1, 0, 32768);
    __syncthreads();
    #pragma unroll
    for (int p = 0; p < 8; ++p) {
        int g = t + 256 * p;
        int c = g >> 4, j = g & 15;
        uint4 wv = *(const uint4*)(wpT + (size_t)c * 384 + 128 + j * 8);
        *(uint4*)(smem + c * 256 + ((j * 16) ^ ((c & 7) << 4))) = wv;
    }
    __syncthreads();
    MM256(acc2, 0, 32768);
    __syncthreads();

    #pragma unroll
    for (int cf = 0; cf < 2; ++cf)
        #pragma unroll
        for (int eb = 0; eb < 4; ++eb) {
            int e  = eb * 16 + lr;
            int c0 = w * 32 + cf * 16 + lg * 4;
            uint2 v1 = { pk2bf(acc1[cf][eb][0], acc1[cf][eb][1]),
                         pk2bf(acc1[cf][eb][2], acc1[cf][eb][3]) };
            *(uint2*)(smem + e * 256 + ((c0 * 2) ^ ((e & 7) << 4))) = v1;
            uint2 v2 = { pk2bf(acc2[cf][eb][0] + sb[c0 + 0], acc2[cf][eb][1] + sb[c0 + 1]),
                         pk2bf(acc2[cf][eb][2] + sb[c0 + 2], acc2[cf][eb][3] + sb[c0 + 3]) };
            *(uint2*)(smem + 16384 + e * 256 + ((c0 * 2) ^ ((e & 7) << 4))) = v2;
        }
    __syncthreads();
    #pragma unroll
    for (int p = 0; p < 4; ++p) {
        int e = (t >> 4) + p * 16;
        int q = t & 15;
        int n = n0 + e;
        if (n < N_NODES) {
            int qq = q ^ (e & 7);
            uint4 v1 = *(const uint4*)(smem + e * 256 + q * 16);
            *(uint4*)(p1 + (size_t)n * D + qq * 8) = v1;
            uint4 v2 = *(const uint4*)(smem + 16384 + e * 256 + q * 16);
            *(uint4*)(p2 + (size_t)n * D + qq * 8) = v2;
        }
    }
}

// ---------------- k_edge: CK=64, 24KB LDS (6 blocks/CU), direct P1/P2 gathers ----------
// E = ef@We (ef sequential); msg = relu(E + P1[src] + P2[dst]) -> msgG (natural order).
__global__ __launch_bounds__(256) void k_edge(
    const float* __restrict__ ef, const unsigned short* __restrict__ wpT,
    const int* __restrict__ src, const int* __restrict__ dst,
    const unsigned short* __restrict__ p1, const unsigned short* __restrict__ p2,
    unsigned short* __restrict__ msgG)
{
    __shared__ __align__(16) char smem[24576]; // W 16KB @0, z 8KB @16384 | msg 16KB @0
    __shared__ int sidx[64], didx[64];

    int t = threadIdx.x;
    int e0 = blockIdx.x * 64;
    if (t < 64) { sidx[t] = src[e0 + t]; didx[t] = dst[e0 + t]; }
    int w = t >> 6, l = t & 63, lr = l & 15, lg = l >> 4;

    f32x4 acc[2][4];
    #pragma unroll
    for (int i = 0; i < 2; ++i)
        #pragma unroll
        for (int j = 0; j < 4; ++j) acc[i][j] = (f32x4){0.f, 0.f, 0.f, 0.f};

    uint4  pw0, pw1, pw2, pw3;
    float4 pz0, pz1, pz2, pz3;

#define EPF(CH) do { \
    { int g = t;       int c = g >> 3, j = g & 7;  pw0 = *(const uint4*)(wpT + (size_t)c * 384 + 256 + (CH) * 64 + j * 8); } \
    { int g = t + 256; int c = g >> 3, j = g & 7;  pw1 = *(const uint4*)(wpT + (size_t)c * 384 + 256 + (CH) * 64 + j * 8); } \
    { int g = t + 512; int c = g >> 3, j = g & 7;  pw2 = *(const uint4*)(wpT + (size_t)c * 384 + 256 + (CH) * 64 + j * 8); } \
    { int g = t + 768; int c = g >> 3, j = g & 7;  pw3 = *(const uint4*)(wpT + (size_t)c * 384 + 256 + (CH) * 64 + j * 8); } \
    { int g = t;       int e = g >> 4, q = g & 15; pz0 = *(const float4*)(ef + (size_t)(e0 + e) * D + (CH) * 64 + q * 4); } \
    { int g = t + 256; int e = g >> 4, q = g & 15; pz1 = *(const float4*)(ef + (size_t)(e0 + e) * D + (CH) * 64 + q * 4); } \
    { int g = t + 512; int e = g >> 4, q = g & 15; pz2 = *(const float4*)(ef + (size_t)(e0 + e) * D + (CH) * 64 + q * 4); } \
    { int g = t + 768; int e = g >> 4, q = g & 15; pz3 = *(const float4*)(ef + (size_t)(e0 + e) * D + (CH) * 64 + q * 4); } \
} while (0)
#define EWR() do { \
    { int g = t;       int c = g >> 3, j = g & 7;  *(uint4*)(smem + c * 128 + ((j * 16) ^ ((c & 7) << 4))) = pw0; } \
    { int g = t + 256; int c = g >> 3, j = g & 7;  *(uint4*)(smem + c * 128 + ((j * 16) ^ ((c & 7) << 4))) = pw1; } \
    { int g = t + 512; int c = g >> 3, j = g & 7;  *(uint4*)(smem + c * 128 + ((j * 16) ^ ((c & 7) << 4))) = pw2; } \
    { int g = t + 768; int c = g >> 3, j = g & 7;  *(uint4*)(smem + c * 128 + ((j * 16) ^ ((c & 7) << 4))) = pw3; } \
    { int g = t;       int e = g >> 4, q = g & 15; uint2 hv = { pk2bf(pz0.x, pz0.y), pk2bf(pz0.z, pz0.w) }; \
      *(uint2*)(smem + 16384 + e * 128 + ((q * 8) ^ ((e & 7) << 4))) = hv; } \
    { int g = t + 256; int e = g >> 4, q = g & 15; uint2 hv = { pk2bf(pz1.x, pz1.y), pk2bf(pz1.z, pz1.w) }; \
      *(uint2*)(smem + 16384 + e * 128 + ((q * 8) ^ ((e & 7) << 4))) = hv; } \
    { int g = t + 512; int e = g >> 4, q = g & 15; uint2 hv = { pk2bf(pz2.x, pz2.y), pk2bf(pz2.z, pz2.w) }; \
      *(uint2*)(smem + 16384 + e * 128 + ((q * 8) ^ ((e & 7) << 4))) = hv; } \
    { int g = t + 768; int e = g >> 4, q = g & 15; uint2 hv = { pk2bf(pz3.x, pz3.y), pk2bf(pz3.z, pz3.w) }; \
      *(uint2*)(smem + 16384 + e * 128 + ((q * 8) ^ ((e & 7) << 4))) = hv; } \
} while (0)
#define EMM() do { \
    _Pragma("unroll") \
    for (int ks = 0; ks < 2; ++ks) { \
        bf16x8 afr[2], bfr[4]; \
        int kb = ks * 64 + lg * 16; \
        _Pragma("unroll") \
        for (int cf = 0; cf < 2; ++cf) { \
            int c = w * 32 + cf * 16 + lr; \
            afr[cf] = *(const bf16x8*)(smem + c * 128 + (kb ^ ((c & 7) << 4))); \
        } \
        _Pragma("unroll") \
        for (int eb = 0; eb < 4; ++eb) { \
            int e = eb * 16 + lr; \
            bfr[eb] = *(const bf16x8*)(smem + 16384 + e * 128 + (kb ^ ((e & 7) << 4))); \
        } \
        _Pragma("unroll") \
        for (int cf = 0; cf < 2; ++cf) \
            _Pragma("unroll") \
            for (int eb = 0; eb < 4; ++eb) \
                acc[cf][eb] = __builtin_amdgcn_mfma_f32_16x16x32_bf16( \
                    afr[cf], bfr[eb], acc[cf][eb], 0, 0, 0); \
    } \
} while (0)

    EPF(0);
    EWR(); EPF(1); __syncthreads(); EMM(); __syncthreads();
    EWR();         __syncthreads(); EMM(); __syncthreads();
#undef EPF
#undef EWR
#undef EMM

    // epilogue: per-lane uint2 gathers from L3-resident P1/P2 + relu -> msg tile @0
    #pragma unroll
    for (int cf = 0; cf < 2; ++cf)
        #pragma unroll
        for (int eb = 0; eb < 4; ++eb) {
            int e  = eb * 16 + lr;
            int c0 = w * 32 + cf * 16 + lg * 4;
            uint2 a1 = *(const uint2*)(p1 + (size_t)sidx[e] * D + c0);
            uint2 a2 = *(const uint2*)(p2 + (size_t)didx[e] * D + c0);
            float v0 = acc[cf][eb][0] + bf2f((unsigned short)(a1.x & 0xffff)) + bf2f((unsigned short)(a2.x & 0xffff));
            float v1 = acc[cf][eb][1] + bf2f((unsigned short)(a1.x >> 16))    + bf2f((unsigned short)(a2.x >> 16));
            float v2 = acc[cf][eb][2] + bf2f((unsigned short)(a1.y & 0xffff)) + bf2f((unsigned short)(a2.y & 0xffff));
            float v3 = acc[cf][eb][3] + bf2f((unsigned short)(a1.y >> 16))    + bf2f((unsigned short)(a2.y >> 16));
            uint2 mv = { pk2bf(fmaxf(v0, 0.f), fmaxf(v1, 0.f)),
                         pk2bf(fmaxf(v2, 0.f), fmaxf(v3, 0.f)) };
            *(uint2*)(smem + e * 256 + ((c0 * 2) ^ ((e & 7) << 4))) = mv;
        }
    __syncthreads();
    #pragma unroll
    for (int p = 0; p < 4; ++p) {
        int e = (t >> 4) + p * 16;
        int q = t & 15;
        uint4 v = *(const uint4*)(smem + e * 256 + q * 16);
        int qq = q ^ (e & 7);
        *(uint4*)(msgG + (size_t)(e0 + e) * D + qq * 8) = v;
    }
}

// ---------------- k_agg: perm preloaded lane-parallel + shfl broadcast ----------------
__global__ __launch_bounds__(256) void k_agg(
    const unsigned short* __restrict__ msgG,
    const int* __restrict__ cursor, const int* __restrict__ hist,
    const int* __restrict__ perm,
    float* __restrict__ s1, float* __restrict__ s2,
    float* __restrict__ mx, float* __restrict__ mn, float* __restrict__ scal)
{
    int t = threadIdx.x;
    int n = blockIdx.x * 4 + (t >> 6);
    int tl = t & 63;
    int deg = hist[n];
    int re  = cursor[n];          // after k_scatter, cursor[n] == row end
    int rs  = re - deg;

    float sum0 = 0.f, sum1 = 0.f, sq0 = 0.f, sq1 = 0.f;
    float mx0 = -3.402823e38f, mx1 = -3.402823e38f;
    float mn0 =  3.402823e38f, mn1 =  3.402823e38f;
    const uint* mg = (const uint*)msgG;

    // preload up to 64 perm indices (coalesced, one per lane); broadcast via shfl
    int pe_lane = (tl < deg) ? perm[rs + tl] : 0;
    int dmin = (deg < 64) ? deg : 64;
    for (int e = 0; e < dmin; ++e) {
        int pe = __shfl(pe_lane, e);
        uint v = mg[(size_t)pe * 64 + tl];
        float a = bf2f((unsigned short)(v & 0xffff));
        float b = bf2f((unsigned short)(v >> 16));
        sum0 += a; sum1 += b; sq0 += a * a; sq1 += b * b;
        mx0 = fmaxf(mx0, a); mx1 = fmaxf(mx1, b);
        mn0 = fminf(mn0, a); mn1 = fminf(mn1, b);
    }
    for (int e = 64; e < deg; ++e) {   // rare high-degree tail
        int pe = perm[rs + e];
        uint v = mg[(size_t)pe * 64 + tl];
        float a = bf2f((unsigned short)(v & 0xffff));
        float b = bf2f((unsigned short)(v >> 16));
        sum0 += a; sum1 += b; sq0 += a * a; sq1 += b * b;
        mx0 = fmaxf(mx0, a); mx1 = fmaxf(mx1, b);
        mn0 = fminf(mn0, a); mn1 = fminf(mn1, b);
    }
    float dg = (float)deg;
    float ds = fmaxf(dg, 1.f);
    bool nb = deg > 0;
    float m0 = sum0 / ds, m1 = sum1 / ds;
    float sd0 = sqrtf(fmaxf(sq0 / ds - m0 * m0, 0.f) + EPS);
    float sd1 = sqrtf(fmaxf(sq1 / ds - m1 * m1, 0.f) + EPS);
    size_t base = (size_t)n * D + tl * 2;
    *(float2*)&s1[base] = (float2){m0, m1};
    *(float2*)&s2[base] = (float2){sd0, sd1};
    *(float2*)&mx[base] = (float2){nb ? mx0 : 0.f, nb ? mx1 : 0.f};
    *(float2*)&mn[base] = (float2){nb ? mn0 : 0.f, nb ? mn1 : 0.f};
    if (tl == 0) {
        float logd = logf(dg + 1.f);
        scal[2 * n]     = logd / AVG_D_LOG;
        scal[2 * n + 1] = AVG_D_LOG / fmaxf(logd, EPS);
    }
}

// staging macros for the fallback fused pretrans
#define PFN(NC, PW0, PW1, PW2, PW3, PZ0, PZ1, PZ2, PZ3) do { \
    { int g = t;       int c = g >> 3, j = g & 7;  PW0 = *(const uint4*)(wpT + (size_t)c * 384 + (NC) * 64 + j * 8); } \
    { int g = t + 256; int c = g >> 3, j = g & 7;  PW1 = *(const uint4*)(wpT + (size_t)c * 384 + (NC) * 64 + j * 8); } \
    { int g = t + 512; int c = g >> 3, j = g & 7;  PW2 = *(const uint4*)(wpT + (size_t)c * 384 + (NC) * 64 + j * 8); } \
    { int g = t + 768; int c = g >> 3, j = g & 7;  PW3 = *(const uint4*)(wpT + (size_t)c * 384 + (NC) * 64 + j * 8); } \
    { int g = t;       int e = g >> 4, q = g & 15; PZ0 = *(const float4*)(ZROW(NC, e) + (((NC) & 1) * 64) + q * 4); } \
    { int g = t + 256; int e = g >> 4, q = g & 15; PZ1 = *(const float4*)(ZROW(NC, e) + (((NC) & 1) * 64) + q * 4); } \
    { int g = t + 512; int e = g >> 4, q = g & 15; PZ2 = *(const float4*)(ZROW(NC, e) + (((NC) & 1) * 64) + q * 4); } \
    { int g = t + 768; int e = g >> 4, q = g & 15; PZ3 = *(const float4*)(ZROW(NC, e) + (((NC) & 1) * 64) + q * 4); } \
} while (0)
#define WRN(OFF, PW0, PW1, PW2, PW3, PZ0, PZ1, PZ2, PZ3) do { \
    { int g = t;       int c = g >> 3, j = g & 7;  *(uint4*)(smem + (OFF) + c * 128 + ((j * 16) ^ ((c & 7) << 4))) = PW0; } \
    { int g = t + 256; int c = g >> 3, j = g & 7;  *(uint4*)(smem + (OFF) + c * 128 + ((j * 16) ^ ((c & 7) << 4))) = PW1; } \
    { int g = t + 512; int c = g >> 3, j = g & 7;  *(uint4*)(smem + (OFF) + c * 128 + ((j * 16) ^ ((c & 7) << 4))) = PW2; } \
    { int g = t + 768; int c = g >> 3, j = g & 7;  *(uint4*)(smem + (OFF) + c * 128 + ((j * 16) ^ ((c & 7) << 4))) = PW3; } \
    { int g = t;       int e = g >> 4, q = g & 15; uint2 hv = { pk2bf(PZ0.x, PZ0.y), pk2bf(PZ0.z, PZ0.w) }; \
      *(uint2*)(smem + (OFF) + 16384 + e * 128 + ((q * 8) ^ ((e & 7) << 4))) = hv; } \
    { int g = t + 256; int e = g >> 4, q = g & 15; uint2 hv = { pk2bf(PZ1.x, PZ1.y), pk2bf(PZ1.z, PZ1.w) }; \
      *(uint2*)(smem + (OFF) + 16384 + e * 128 + ((q * 8) ^ ((e & 7) << 4))) = hv; } \
    { int g = t + 512; int e = g >> 4, q = g & 15; uint2 hv = { pk2bf(PZ2.x, PZ2.y), pk2bf(PZ2.z, PZ2.w) }; \
      *(uint2*)(smem + (OFF) + 16384 + e * 128 + ((q * 8) ^ ((e & 7) << 4))) = hv; } \
    { int g = t + 768; int e = g >> 4, q = g & 15; uint2 hv = { pk2bf(PZ3.x, PZ3.y), pk2bf(PZ3.z, PZ3.w) }; \
      *(uint2*)(smem + (OFF) + 16384 + e * 128 + ((q * 8) ^ ((e & 7) << 4))) = hv; } \
} while (0)
#define MMO(OFF) do { \
    _Pragma("unroll") \
    for (int ks = 0; ks < 2; ++ks) { \
        bf16x8 afr[2], bfr[4]; \
        int kb = ks * 64 + lg * 16; \
        _Pragma("unroll") \
        for (int cf = 0; cf < 2; ++cf) { \
            int c = w * 32 + cf * 16 + lr; \
            afr[cf] = *(const bf16x8*)(smem + (OFF) + c * 128 + (kb ^ ((c & 7) << 4))); \
        } \
        _Pragma("unroll") \
        for (int eb = 0; eb < 4; ++eb) { \
            int e = eb * 16 + lr; \
            bfr[eb] = *(const bf16x8*)(smem + (OFF) + 16384 + e * 128 + (kb ^ ((e & 7) << 4))); \
        } \
        _Pragma("unroll") \
        for (int cf = 0; cf < 2; ++cf) \
            _Pragma("unroll") \
            for (int eb = 0; eb < 4; ++eb) \
                acc[cf][eb] = __builtin_amdgcn_mfma_f32_16x16x32_bf16( \
                    afr[cf], bfr[eb], acc[cf][eb], 0, 0, 0); \
    } \
} while (0)

// ---------------- fallback: fused pretrans (all-atomic epilogue) ----------------
__global__ __launch_bounds__(256) void k_pretrans(
    const float* __restrict__ nf, const float* __restrict__ ef,
    const unsigned short* __restrict__ wpT, const float* __restrict__ bp,
    const int* __restrict__ src, const int* __restrict__ dst,
    const int* __restrict__ perm,
    float* s1, float* s2, float* mx, float* mn)
{
    __shared__ __align__(16) char smem[24576];
    __shared__ int pidx[64], sidx[64], didx[64];
    __shared__ int seg_start[65], seg_dst[64];
    __shared__ int nseg_s;
    __shared__ float sb[128];

    int t = threadIdx.x;
    int e0 = blockIdx.x * 64;
    if (t < 64) {
        int pe = perm[e0 + t];
        pidx[t] = pe; sidx[t] = src[pe]; didx[t] = dst[pe];
    }
    if (t < 128) sb[t] = bp[t];
    __syncthreads();

    int w  = t >> 6;
    int l  = t & 63;
    int lr = l & 15;
    int lg = l >> 4;

    f32x4 acc[2][4];
    #pragma unroll
    for (int i = 0; i < 2; ++i)
        #pragma unroll
        for (int j = 0; j < 4; ++j) acc[i][j] = (f32x4){0.f, 0.f, 0.f, 0.f};

    uint4  pw0, pw1, pw2, pw3;
    float4 pz0, pz1, pz2, pz3;

#define ZROW(NC, e) ((NC) < 2 ? nf + (size_t)sidx[e] * D : \
                     (NC) < 4 ? nf + (size_t)didx[e] * D : \
                                ef + (size_t)pidx[e] * D)
    PFN(0, pw0, pw1, pw2, pw3, pz0, pz1, pz2, pz3);
    WRN(0, pw0, pw1, pw2, pw3, pz0, pz1, pz2, pz3); PFN(1, pw0, pw1, pw2, pw3, pz0, pz1, pz2, pz3); __syncthreads(); MMO(0); __syncthreads();
    WRN(0, pw0, pw1, pw2, pw3, pz0, pz1, pz2, pz3); PFN(2, pw0, pw1, pw2, pw3, pz0, pz1, pz2, pz3); __syncthreads(); MMO(0); __syncthreads();
    WRN(0, pw0, pw1, pw2, pw3, pz0, pz1, pz2, pz3); PFN(3, pw0, pw1, pw2, pw3, pz0, pz1, pz2, pz3); __syncthreads(); MMO(0); __syncthreads();
    WRN(0, pw0, pw1, pw2, pw3, pz0, pz1, pz2, pz3); PFN(4, pw0, pw1, pw2, pw3, pz0, pz1, pz2, pz3); __syncthreads(); MMO(0); __syncthreads();
    WRN(0, pw0, pw1, pw2, pw3, pz0, pz1, pz2, pz3); PFN(5, pw0, pw1, pw2, pw3, pz0, pz1, pz2, pz3); __syncthreads(); MMO(0); __syncthreads();
    WRN(0, pw0, pw1, pw2, pw3, pz0, pz1, pz2, pz3);                                                 __syncthreads(); MMO(0); __syncthreads();
#undef ZROW

    #pragma unroll
    for (int cf = 0; cf < 2; ++cf)
        #pragma unroll
        for (int eb = 0; eb < 4; ++eb) {
            int e  = eb * 16 + lr;
            int c0 = w * 32 + cf * 16 + lg * 4;
            float v0 = fmaxf(acc[cf][eb][0] + sb[c0 + 0], 0.f);
            float v1 = fmaxf(acc[cf][eb][1] + sb[c0 + 1], 0.f);
            float v2 = fmaxf(acc[cf][eb][2] + sb[c0 + 2], 0.f);
            float v3 = fmaxf(acc[cf][eb][3] + sb[c0 + 3], 0.f);
            uint2 mv = { pk2bf(v0, v1), pk2bf(v2, v3) };
            *(uint2*)(smem + e * 256 + ((c0 * 2) ^ ((e & 7) << 4))) = mv;
        }
    if (t == 0) {
        int ns = 0;
        for (int e = 0; e < 64; ++e) {
            if (e == 0 || didx[e] != didx[e - 1]) { seg_dst[ns] = didx[e]; seg_start[ns] = e; ++ns; }
        }
        seg_start[ns] = 64; nseg_s = ns;
    }
    __syncthreads();
    int nseg = nseg_s;
    for (int idx = t; idx < nseg * D; idx += 256) {
        int sg = idx >> 7, c = idx & 127;
        int eb2 = seg_start[sg], ee = seg_start[sg + 1];
        float s = 0.f, q = 0.f, vmax = 0.f, vmin = __int_as_float(0x7f800000);
        for (int e = eb2; e < ee; ++e) {
            float v = bf2f(*(const unsigned short*)(smem + e * 256 + ((c * 2) ^ ((e & 7) << 4))));
            s += v; q += v * v;
            vmax = fmaxf(vmax, v); vmin = fminf(vmin, v);
        }
        size_t base = (size_t)seg_dst[sg] * D + c;
        atomicAdd(&s1[base], s);
        atomicAdd(&s2[base], q);
        atomicMax((int*)&mx[base], __float_as_int(vmax));
        atomicMin((int*)&mn[base], __float_as_int(vmin));
    }
}

#undef PFN
#undef WRN
#undef MMO

// ---------------- fallback: finalize in place + scalers ----------------
__global__ void k_finalize(float* s1, float* s2, float* mx, float* mn,
                           const int* __restrict__ hist, float* scal) {
    size_t idx = (size_t)blockIdx.x * blockDim.x + threadIdx.x;
    if (idx >= (size_t)N_NODES * D) return;
    int n = (int)(idx >> 7);
    int c = (int)(idx & 127);
    float dg = (float)hist[n];
    float ds = fmaxf(dg, 1.f);
    float m  = s1[idx] / ds;
    float var = fmaxf(s2[idx] / ds - m * m, 0.f);
    float sd  = sqrtf(var + EPS);
    bool nb = dg > 0.f;
    s1[idx] = m;
    mx[idx] = nb ? mx[idx] : 0.f;
    mn[idx] = nb ? mn[idx] : 0.f;
    s2[idx] = sd;
    if (c == 0) {
        float logd = logf(dg + 1.f);
        scal[2 * n]     = logd / AVG_D_LOG;
        scal[2 * n + 1] = AVG_D_LOG / fmaxf(logd, EPS);
    }
}

// ---------------- fused posttrans: out = relu(h@W1+b1)@W2 + b2 + nf ----------------
__global__ __launch_bounds__(256, 3) void k_post(
    const float* __restrict__ nf,
    const float* __restrict__ amean, const float* __restrict__ amax,
    const float* __restrict__ amin,  const float* __restrict__ astd,
    const float* __restrict__ scal,
    const unsigned short* __restrict__ w1T, const float* __restrict__ b1,
    const unsigned short* __restrict__ w2T, const float* __restrict__ b2,
    float* __restrict__ out)
{
    __shared__ __align__(16) char smem[49152];
    __shared__ float samp[64], satt[64], sb1[128], sb2[128];

    int t = threadIdx.x;
    int n0 = blockIdx.x * 64;
    if (t < 64) {
        int n = n0 + t;
        samp[t] = (n < N_NODES) ? scal[2 * n] : 0.f;
        satt[t] = (n < N_NODES) ? scal[2 * n + 1] : 0.f;
    }
    if (t < 128) { sb1[t] = b1[t]; sb2[t] = b2[t]; }
    __syncthreads();

    int w  = t >> 6, l = t & 63, lr = l & 15, lg = l >> 4;
    f32x4 acc[2][4];
    #pragma unroll
    for (int i = 0; i < 2; ++i)
        #pragma unroll
        for (int j = 0; j < 4; ++j) acc[i][j] = (f32x4){0.f, 0.f, 0.f, 0.f};

    for (int chunk = 0; chunk < 13; ++chunk) {
        #pragma unroll
        for (int p = 0; p < 8; ++p) {
            int g = t + 256 * p;
            int c = g >> 4, j = g & 15;
            uint4 wv = *(const uint4*)(w1T + (size_t)c * 1664 + chunk * 128 + j * 8);
            *(uint4*)(smem + c * 256 + ((j * 16) ^ ((c & 7) << 4))) = wv;
        }
        const float* base;
        int r;
        if (chunk == 0) { base = nf; r = 0; }
        else {
            int b = (chunk - 1) & 3;
            r = (chunk - 1) >> 2;
            base = (b == 0) ? amean : (b == 1) ? amax : (b == 2) ? amin : astd;
        }
        #pragma unroll
        for (int p = 0; p < 8; ++p) {
            int g = t + 256 * p;
            int e = g >> 5, q = g & 31;
            int n = n0 + e;
            float4 fv = {0.f, 0.f, 0.f, 0.f};
            if (n < N_NODES) {
                fv = *(const float4*)(base + (size_t)n * D + q * 4);
                if (r == 1) { float sc = samp[e]; fv.x *= sc; fv.y *= sc; fv.z *= sc; fv.w *= sc; }
                else if (r == 2) { float sc = satt[e]; fv.x *= sc; fv.y *= sc; fv.z *= sc; fv.w *= sc; }
            }
            uint2 hv = { pk2bf(fv.x, fv.y), pk2bf(fv.z, fv.w) };
            *(uint2*)(smem + 32768 + e * 256 + ((q * 8) ^ ((e & 7) << 4))) = hv;
        }
        __syncthreads();
        MM256(acc, 0, 32768);
        __syncthreads();
    }

    // h1 = relu(acc + b1) -> LDS B-layout @32768
    #pragma unroll
    for (int cf = 0; cf < 2; ++cf)
        #pragma unroll
        for (int eb = 0; eb < 4; ++eb) {
            int e  = eb * 16 + lr;
            int c0 = w * 32 + cf * 16 + lg * 4;
            float v0 = fmaxf(acc[cf][eb][0] + sb1[c0 + 0], 0.f);
            float v1 = fmaxf(acc[cf][eb][1] + sb1[c0 + 1], 0.f);
            float v2 = fmaxf(acc[cf][eb][2] + sb1[c0 + 2], 0.f);
            float v3 = fmaxf(acc[cf][eb][3] + sb1[c0 + 3], 0.f);
            uint2 hv = { pk2bf(v0, v1), pk2bf(v2, v3) };
            *(uint2*)(smem + 32768 + e * 256 + ((c0 * 2) ^ ((e & 7) << 4))) = hv;
        }
    #pragma unroll
    for (int p = 0; p < 8; ++p) {
        int g = t + 256 * p;
        int c = g >> 4, j = g & 15;
        uint4 wv = *(const uint4*)(w2T + (size_t)c * 128 + j * 8);
        *(uint4*)(smem + c * 256 + ((j * 16) ^ ((c & 7) << 4))) = wv;
    }
    __syncthreads();

    f32x4 acc2[2][4];
    #pragma unroll
    for (int i = 0; i < 2; ++i)
        #pragma unroll
        for (int j = 0; j < 4; ++j) acc2[i][j] = (f32x4){0.f, 0.f, 0.f, 0.f};
    MM256(acc2, 0, 32768);

    #pragma unroll
    for (int cf = 0; cf < 2; ++cf)
        #pragma unroll
        for (int eb = 0; eb < 4; ++eb) {
            int n = n0 + eb * 16 + lr;
            if (n < N_NODES) {
                int c0 = w * 32 + cf * 16 + lg * 4;
                float4 rv = *(const float4*)(nf + (size_t)n * D + c0);
                float4 ov = { acc2[cf][eb][0] + sb2[c0 + 0] + rv.x,
                              acc2[cf][eb][1] + sb2[c0 + 1] + rv.y,
                              acc2[cf][eb][2] + sb2[c0 + 2] + rv.z,
                              acc2[cf][eb][3] + sb2[c0 + 3] + rv.w };
                *(float4*)(out + (size_t)n * D + c0) = ov;
            }
        }
}

extern "C" void kernel_launch(void* const* d_in, const int* in_sizes, int n_in,
                              void* d_out, int out_size, void* d_ws, size_t ws_size,
                              hipStream_t stream) {
    const float* nf = (const float*)d_in[0];
    const float* ef = (const float*)d_in[1];
    const float* wp = (const float*)d_in[2];
    const float* bp = (const float*)d_in[3];
    const float* w1 = (const float*)d_in[4];
    const float* b1 = (const float*)d_in[5];
    const float* w2 = (const float*)d_in[6];
    const float* b2 = (const float*)d_in[7];
    const int* src  = (const int*)d_in[8];
    const int* dst  = (const int*)d_in[9];
    float* out = (float*)d_out;

    const size_t ND = (size_t)N_NODES * D;       // 6.4M
    const size_t MSG_SH = (size_t)N_EDGES * D;   // 102.4M ushorts
    char* wsb = (char*)d_ws;
    int*   hist   = (int*)wsb;                                   // 50048
    int*   cursor = hist + 50048;                                // 50048
    int*   perm   = cursor + 50048;                              // 800000
    unsigned short* wpT = (unsigned short*)(perm + N_EDGES);     // 49152
    unsigned short* w1T = wpT + 49152;                           // 212992
    unsigned short* w2T = w1T + 212992;                          // 16384
    unsigned short* tail = w2T + 16384;

    // CSR layout
    unsigned short* p1   = tail;                 // ND bf16
    unsigned short* p2   = p1 + ND;              // ND bf16
    unsigned short* msgG = p2 + ND;              // MSG_SH bf16
    float* s1   = (float*)(msgG + MSG_SH);
    float* s2   = s1 + ND;
    float* mx   = s2 + ND;
    float* mn   = mx + ND;
    float* scal = mn + ND;
    size_t need_csr = (size_t)((char*)(scal + 100096) - wsb);

    bool use_csr = ws_size >= need_csr;
    if (!use_csr) {
        s1   = (float*)tail;
        s2   = s1 + ND;
        mx   = s2 + ND;
        mn   = mx + ND;
        scal = mn + ND;
    }

    if (use_csr) {
        hipMemsetAsync(hist, 0, N_NODES * sizeof(int), stream);
    } else {
        hipLaunchKernelGGL(k_init, dim3(2048), dim3(256), 0, stream, hist, s1, s2, mx, mn);
    }
    hipLaunchKernelGGL(k_prep, dim3(1088 + (N_EDGES + 255) / 256), dim3(256), 0, stream,
                       wp, w1, w2, wpT, w1T, w2T, dst, hist);
    hipLaunchKernelGGL(k_scan, dim3(1), dim3(1024), 0, stream, hist, cursor);
    hipLaunchKernelGGL(k_scatter, dim3((N_EDGES + 255) / 256), dim3(256), 0, stream, dst, cursor, perm);
    if (use_csr) {
        hipLaunchKernelGGL(k_node, dim3((N_NODES + 63) / 64), dim3(256), 0, stream,
                           nf, wpT, bp, p1, p2);
        hipLaunchKernelGGL(k_edge, dim3(N_EDGES / 64), dim3(256), 0, stream,
                           ef, wpT, src, dst, p1, p2, msgG);
        hipLaunchKernelGGL(k_agg, dim3(N_NODES / 4), dim3(256), 0, stream,
                           msgG, cursor, hist, perm, s1, s2, mx, mn, scal);
    } else {
        hipLaunchKernelGGL(k_pretrans, dim3(N_EDGES / 64), dim3(256), 0, stream,
                           nf, ef, wpT, bp, src, dst, perm, s1, s2, mx, mn);
        hipLaunchKernelGGL(k_finalize, dim3((unsigned)((ND + 255) / 256)), dim3(256), 0, stream,
                           s1, s2, mx, mn, hist, scal);
    }
    hipLaunchKernelGGL(k_post, dim3((N_NODES + 63) / 64), dim3(256), 0, stream,
                       nf, s1, mx, mn, s2, scal, w1T, b1, w2T, b2, out);
}

// Round 17
// 558.389 us; speedup vs baseline: 2.3077x; 1.0502x over previous
//
#include <hip/hip_runtime.h>
#include <math.h>

#define N_NODES 50000
#define N_EDGES 800000
#define D 128
#define AVG_D_LOG 2.833213344056216f  /* log(17.0) */
#define EPS 1e-5f

typedef __attribute__((ext_vector_type(8))) short bf16x8;
typedef __attribute__((ext_vector_type(4))) float f32x4;

__device__ __forceinline__ unsigned short f2bf(float x) {
    unsigned u = __float_as_uint(x);
    u += 0x7fffu + ((u >> 16) & 1u);
    return (unsigned short)(u >> 16);
}
__device__ __forceinline__ unsigned pk2bf(float a, float b) {
    return (unsigned)f2bf(a) | ((unsigned)f2bf(b) << 16);
}
__device__ __forceinline__ float bf2f(unsigned short u) {
    return __uint_as_float(((unsigned)u) << 16);
}

// ---------------- init (fallback only) ----------------
__global__ void k_init(int* hist, float* s1, float* s2, float* mx, float* mn) {
    size_t stride = (size_t)gridDim.x * blockDim.x;
    size_t i0 = (size_t)blockIdx.x * blockDim.x + threadIdx.x;
    const size_t ND4 = (size_t)N_NODES * D / 4;
    float4 z4 = {0.f, 0.f, 0.f, 0.f};
    int4 inf4 = {0x7f800000, 0x7f800000, 0x7f800000, 0x7f800000};
    for (size_t t = i0; t < ND4; t += stride) {
        ((float4*)s1)[t] = z4; ((float4*)s2)[t] = z4; ((float4*)mx)[t] = z4;
        ((int4*)mn)[t] = inf4;
    }
    for (size_t t = i0; t < N_NODES; t += stride) hist[t] = 0;
}

// ---------------- fused prep: 3 weight transposes + dst histogram ----------------
__global__ void k_prep(const float* __restrict__ wp, const float* __restrict__ w1,
                       const float* __restrict__ w2,
                       unsigned short* __restrict__ wpT, unsigned short* __restrict__ w1T,
                       unsigned short* __restrict__ w2T,
                       const int* __restrict__ dst, int* hist) {
    int b = blockIdx.x, t = threadIdx.x;
    if (b < 192) {
        int idx = b * 256 + t;
        int k = idx >> 7, c = idx & 127;
        wpT[(size_t)c * 384 + k] = f2bf(wp[idx]);
    } else if (b < 1024) {
        int idx = (b - 192) * 256 + t;
        int k = idx >> 7, c = idx & 127;
        w1T[(size_t)c * 1664 + k] = f2bf(w1[idx]);
    } else if (b < 1088) {
        int idx = (b - 1024) * 256 + t;
        int k = idx >> 7, c = idx & 127;
        w2T[(size_t)c * 128 + k] = f2bf(w2[idx]);
    } else {
        int e = (b - 1088) * 256 + t;
        if (e < N_EDGES) atomicAdd(&hist[dst[e]], 1);
    }
}

// ---------------- parallel exclusive scan ----------------
__global__ __launch_bounds__(1024) void k_scan(const int* __restrict__ hist, int* cursor) {
    __shared__ int part[1024];
    int t = threadIdx.x;
    const int chunk = (N_NODES + 1023) / 1024;
    int lo = t * chunk;
    int hi = lo + chunk; if (hi > N_NODES) hi = N_NODES;
    int s = 0;
    for (int i = lo; i < hi; ++i) s += hist[i];
    part[t] = s;
    __syncthreads();
    for (int off = 1; off < 1024; off <<= 1) {
        int v = (t >= off) ? part[t - off] : 0;
        __syncthreads();
        part[t] += v;
        __syncthreads();
    }
    int run = (t == 0) ? 0 : part[t - 1];
    for (int i = lo; i < hi; ++i) { cursor[i] = run; run += hist[i]; }
}

// scatter: perm (for fallback) + rnk = per-edge dst-sorted position (for k_edge)
__global__ void k_scatter(const int* __restrict__ dst, int* cursor, int* perm, int* rnk) {
    int e = blockIdx.x * blockDim.x + threadIdx.x;
    if (e < N_EDGES) {
        int pos = atomicAdd(&cursor[dst[e]], 1);
        perm[pos] = e;
        rnk[e] = pos;
    }
}

// ---- 256B-row-stride MFMA macro (K=128 tiles) ----
#define MM256(ACC, AOFF, BOFF) do { \
    _Pragma("unroll") \
    for (int ks = 0; ks < 4; ++ks) { \
        bf16x8 afr[2], bfr[4]; \
        int kb = ks * 64 + lg * 16; \
        _Pragma("unroll") \
        for (int cf = 0; cf < 2; ++cf) { \
            int c = w * 32 + cf * 16 + lr; \
            afr[cf] = *(const bf16x8*)(smem + (AOFF) + c * 256 + (kb ^ ((c & 7) << 4))); \
        } \
        _Pragma("unroll") \
        for (int eb = 0; eb < 4; ++eb) { \
            int e = eb * 16 + lr; \
            bfr[eb] = *(const bf16x8*)(smem + (BOFF) + e * 256 + (kb ^ ((e & 7) << 4))); \
        } \
        _Pragma("unroll") \
        for (int cf = 0; cf < 2; ++cf) \
            _Pragma("unroll") \
            for (int eb = 0; eb < 4; ++eb) \
                ACC[cf][eb] = __builtin_amdgcn_mfma_f32_16x16x32_bf16( \
                    afr[cf], bfr[eb], ACC[cf][eb], 0, 0, 0); \
    } \
} while (0)

// ---------------- k_node: P1 = nf@Ws, P2 = nf@Wd + b (bf16 out) ----------------
__global__ __launch_bounds__(256) void k_node(
    const float* __restrict__ nf, const unsigned short* __restrict__ wpT,
    const float* __restrict__ bp,
    unsigned short* __restrict__ p1, unsigned short* __restrict__ p2)
{
    __shared__ __align__(16) char smem[49152];
    __shared__ float sb[128];
    int t = threadIdx.x;
    int n0 = blockIdx.x * 64;
    if (t < 128) sb[t] = bp[t];
    int w = t >> 6, l = t & 63, lr = l & 15, lg = l >> 4;

    f32x4 acc1[2][4], acc2[2][4];
    #pragma unroll
    for (int i = 0; i < 2; ++i)
        #pragma unroll
        for (int j = 0; j < 4; ++j) { acc1[i][j] = (f32x4){0.f,0.f,0.f,0.f}; acc2[i][j] = (f32x4){0.f,0.f,0.f,0.f}; }

    #pragma unroll
    for (int p = 0; p < 8; ++p) {
        int g = t + 256 * p;
        int e = g >> 5, q = g & 31;
        int n = n0 + e;
        float4 fv = {0.f, 0.f, 0.f, 0.f};
        if (n < N_NODES) fv = *(const float4*)(nf + (size_t)n * D + q * 4);
        uint2 hv = { pk2bf(fv.x, fv.y), pk2bf(fv.z, fv.w) };
        *(uint2*)(smem + 32768 + e * 256 + ((q * 8) ^ ((e & 7) << 4))) = hv;
    }
    #pragma unroll
    for (int p = 0; p < 8; ++p) {
        int g = t + 256 * p;
        int c = g >> 4, j = g & 15;
        uint4 wv = *(const uint4*)(wpT + (size_t)c * 384 + j * 8);
        *(uint4*)(smem + c * 256 + ((j * 16) ^ ((c & 7) << 4))) = wv;
    }
    __syncthreads();
    MM256(acc1, 0, 32768);
    __syncthreads();
    #pragma unroll
    for (int p = 0; p < 8; ++p) {
        int g = t + 256 * p;
        int c = g >> 4, j = g & 15;
        uint4 wv = *(const uint4*)(wpT + (size_t)c * 384 + 128 + j * 8);
        *(uint4*)(smem + c * 256 + ((j * 16) ^ ((c & 7) << 4))) = wv;
    }
    __syncthreads();
    MM256(acc2, 0, 32768);
    __syncthreads();

    #pragma unroll
    for (int cf = 0; cf < 2; ++cf)
        #pragma unroll
        for (int eb = 0; eb < 4; ++eb) {
            int e  = eb * 16 + lr;
            int c0 = w * 32 + cf * 16 + lg * 4;
            uint2 v1 = { pk2bf(acc1[cf][eb][0], acc1[cf][eb][1]),
                         pk2bf(acc1[cf][eb][2], acc1[cf][eb][3]) };
            *(uint2*)(smem + e * 256 + ((c0 * 2) ^ ((e & 7) << 4))) = v1;
            uint2 v2 = { pk2bf(acc2[cf][eb][0] + sb[c0 + 0], acc2[cf][eb][1] + sb[c0 + 1]),
                         pk2bf(acc2[cf][eb][2] + sb[c0 + 2], acc2[cf][eb][3] + sb[c0 + 3]) };
            *(uint2*)(smem + 16384 + e * 256 + ((c0 * 2) ^ ((e & 7) << 4))) = v2;
        }
    __syncthreads();
    #pragma unroll
    for (int p = 0; p < 4; ++p) {
        int e = (t >> 4) + p * 16;
        int q = t & 15;
        int n = n0 + e;
        if (n < N_NODES) {
            int qq = q ^ (e & 7);
            uint4 v1 = *(const uint4*)(smem + e * 256 + q * 16);
            *(uint4*)(p1 + (size_t)n * D + qq * 8) = v1;
            uint4 v2 = *(const uint4*)(smem + 16384 + e * 256 + q * 16);
            *(uint4*)(p2 + (size_t)n * D + qq * 8) = v2;
        }
    }
}

// ---------------- k_edge (R13-verified structure + rnk-scattered copy-out) ----------------
// E = ef@We (ef sequential); msg = relu(E + P1[src] + P2[dst]);
// copy-out writes each msg row to its dst-sorted position msgG[rnk[e]] (unique -> race-free).
__global__ __launch_bounds__(256) void k_edge(
    const float* __restrict__ ef, const unsigned short* __restrict__ wpT,
    const int* __restrict__ src, const int* __restrict__ dst,
    const int* __restrict__ rnk,
    const unsigned short* __restrict__ p1, const unsigned short* __restrict__ p2,
    unsigned short* __restrict__ msgG)
{
    __shared__ __align__(16) char smem[49152];
    __shared__ int sidx[64], didx[64], ridx[64];

    int t = threadIdx.x;
    int e0 = blockIdx.x * 64;
    if (t < 64) { sidx[t] = src[e0 + t]; didx[t] = dst[e0 + t]; ridx[t] = rnk[e0 + t]; }
    int w = t >> 6, l = t & 63, lr = l & 15, lg = l >> 4;

    f32x4 acc[2][4];
    #pragma unroll
    for (int i = 0; i < 2; ++i)
        #pragma unroll
        for (int j = 0; j < 4; ++j) acc[i][j] = (f32x4){0.f, 0.f, 0.f, 0.f};

    // stage We (k 256..383) @0
    #pragma unroll
    for (int p = 0; p < 8; ++p) {
        int g = t + 256 * p;
        int c = g >> 4, j = g & 15;
        uint4 wv = *(const uint4*)(wpT + (size_t)c * 384 + 256 + j * 8);
        *(uint4*)(smem + c * 256 + ((j * 16) ^ ((c & 7) << 4))) = wv;
    }
    // stage z = ef rows (SEQUENTIAL) @32768
    #pragma unroll
    for (int p = 0; p < 8; ++p) {
        int g = t + 256 * p;
        int e = g >> 5, q = g & 31;
        float4 fv = *(const float4*)(ef + (size_t)(e0 + e) * D + q * 4);
        uint2 hv = { pk2bf(fv.x, fv.y), pk2bf(fv.z, fv.w) };
        *(uint2*)(smem + 32768 + e * 256 + ((q * 8) ^ ((e & 7) << 4))) = hv;
    }
    __syncthreads();   // also publishes sidx/didx/ridx
    MM256(acc, 0, 32768);
    __syncthreads();
    // stage P1[src] @0, P2[dst] @16384 (coalesced 16B over L3-resident arrays)
    #pragma unroll
    for (int p = 0; p < 4; ++p) {
        int g = t + 256 * p;
        int e = g >> 4, q = g & 15;
        uint4 v1 = *(const uint4*)(p1 + (size_t)sidx[e] * D + q * 8);
        *(uint4*)(smem + e * 256 + ((q * 16) ^ ((e & 7) << 4))) = v1;
        uint4 v2 = *(const uint4*)(p2 + (size_t)didx[e] * D + q * 8);
        *(uint4*)(smem + 16384 + e * 256 + ((q * 16) ^ ((e & 7) << 4))) = v2;
    }
    __syncthreads();
    // epilogue: msg = relu(E + P1s + P2d) -> msg tile @32768
    #pragma unroll
    for (int cf = 0; cf < 2; ++cf)
        #pragma unroll
        for (int eb = 0; eb < 4; ++eb) {
            int e  = eb * 16 + lr;
            int c0 = w * 32 + cf * 16 + lg * 4;
            uint2 a1 = *(const uint2*)(smem + e * 256 + ((c0 * 2) ^ ((e & 7) << 4)));
            uint2 a2 = *(const uint2*)(smem + 16384 + e * 256 + ((c0 * 2) ^ ((e & 7) << 4)));
            float v0 = acc[cf][eb][0] + bf2f((unsigned short)(a1.x & 0xffff)) + bf2f((unsigned short)(a2.x & 0xffff));
            float v1 = acc[cf][eb][1] + bf2f((unsigned short)(a1.x >> 16))    + bf2f((unsigned short)(a2.x >> 16));
            float v2 = acc[cf][eb][2] + bf2f((unsigned short)(a1.y & 0xffff)) + bf2f((unsigned short)(a2.y & 0xffff));
            float v3 = acc[cf][eb][3] + bf2f((unsigned short)(a1.y >> 16))    + bf2f((unsigned short)(a2.y >> 16));
            uint2 mv = { pk2bf(fmaxf(v0, 0.f), fmaxf(v1, 0.f)),
                         pk2bf(fmaxf(v2, 0.f), fmaxf(v3, 0.f)) };
            *(uint2*)(smem + 32768 + e * 256 + ((c0 * 2) ^ ((e & 7) << 4))) = mv;
        }
    __syncthreads();
    // copy-out to dst-sorted positions (scattered 256B-row writes, fire-and-forget)
    #pragma unroll
    for (int p = 0; p < 4; ++p) {
        int e = (t >> 4) + p * 16;
        int q = t & 15;
        uint4 v = *(const uint4*)(smem + 32768 + e * 256 + q * 16);
        int qq = q ^ (e & 7);
        *(uint4*)(msgG + (size_t)ridx[e] * D + qq * 8) = v;
    }
}

// ---------------- k_agg: SEQUENTIAL msgG rows (dst-sorted) -> fp32 aggregates ----------
__global__ __launch_bounds__(256) void k_agg(
    const unsigned short* __restrict__ msgG,
    const int* __restrict__ cursor, const int* __restrict__ hist,
    float* __restrict__ s1, float* __restrict__ s2,
    float* __restrict__ mx, float* __restrict__ mn, float* __restrict__ scal)
{
    int t = threadIdx.x;
    int n = blockIdx.x * 4 + (t >> 6);
    int tl = t & 63;
    int deg = hist[n];
    int re  = cursor[n];          // after k_scatter, cursor[n] == row end
    int rs  = re - deg;

    float sum0 = 0.f, sum1 = 0.f, sq0 = 0.f, sq1 = 0.f;
    float mx0 = -3.402823e38f, mx1 = -3.402823e38f;
    float mn0 =  3.402823e38f, mn1 =  3.402823e38f;
    const uint* mg = (const uint*)msgG;
    for (int e = 0; e < deg; ++e) {
        uint v = mg[(size_t)(rs + e) * 64 + tl];
        float a = bf2f((unsigned short)(v & 0xffff));
        float b = bf2f((unsigned short)(v >> 16));
        sum0 += a; sum1 += b; sq0 += a * a; sq1 += b * b;
        mx0 = fmaxf(mx0, a); mx1 = fmaxf(mx1, b);
        mn0 = fminf(mn0, a); mn1 = fminf(mn1, b);
    }
    float dg = (float)deg;
    float ds = fmaxf(dg, 1.f);
    bool nb = deg > 0;
    float m0 = sum0 / ds, m1 = sum1 / ds;
    float sd0 = sqrtf(fmaxf(sq0 / ds - m0 * m0, 0.f) + EPS);
    float sd1 = sqrtf(fmaxf(sq1 / ds - m1 * m1, 0.f) + EPS);
    size_t base = (size_t)n * D + tl * 2;
    *(float2*)&s1[base] = (float2){m0, m1};
    *(float2*)&s2[base] = (float2){sd0, sd1};
    *(float2*)&mx[base] = (float2){nb ? mx0 : 0.f, nb ? mx1 : 0.f};
    *(float2*)&mn[base] = (float2){nb ? mn0 : 0.f, nb ? mn1 : 0.f};
    if (tl == 0) {
        float logd = logf(dg + 1.f);
        scal[2 * n]     = logd / AVG_D_LOG;
        scal[2 * n + 1] = AVG_D_LOG / fmaxf(logd, EPS);
    }
}

// staging macros for the fallback fused pretrans
#define PFN(NC, PW0, PW1, PW2, PW3, PZ0, PZ1, PZ2, PZ3) do { \
    { int g = t;       int c = g >> 3, j = g & 7;  PW0 = *(const uint4*)(wpT + (size_t)c * 384 + (NC) * 64 + j * 8); } \
    { int g = t + 256; int c = g >> 3, j = g & 7;  PW1 = *(const uint4*)(wpT + (size_t)c * 384 + (NC) * 64 + j * 8); } \
    { int g = t + 512; int c = g >> 3, j = g & 7;  PW2 = *(const uint4*)(wpT + (size_t)c * 384 + (NC) * 64 + j * 8); } \
    { int g = t + 768; int c = g >> 3, j = g & 7;  PW3 = *(const uint4*)(wpT + (size_t)c * 384 + (NC) * 64 + j * 8); } \
    { int g = t;       int e = g >> 4, q = g & 15; PZ0 = *(const float4*)(ZROW(NC, e) + (((NC) & 1) * 64) + q * 4); } \
    { int g = t + 256; int e = g >> 4, q = g & 15; PZ1 = *(const float4*)(ZROW(NC, e) + (((NC) & 1) * 64) + q * 4); } \
    { int g = t + 512; int e = g >> 4, q = g & 15; PZ2 = *(const float4*)(ZROW(NC, e) + (((NC) & 1) * 64) + q * 4); } \
    { int g = t + 768; int e = g >> 4, q = g & 15; PZ3 = *(const float4*)(ZROW(NC, e) + (((NC) & 1) * 64) + q * 4); } \
} while (0)
#define WRN(OFF, PW0, PW1, PW2, PW3, PZ0, PZ1, PZ2, PZ3) do { \
    { int g = t;       int c = g >> 3, j = g & 7;  *(uint4*)(smem + (OFF) + c * 128 + ((j * 16) ^ ((c & 7) << 4))) = PW0; } \
    { int g = t + 256; int c = g >> 3, j = g & 7;  *(uint4*)(smem + (OFF) + c * 128 + ((j * 16) ^ ((c & 7) << 4))) = PW1; } \
    { int g = t + 512; int c = g >> 3, j = g & 7;  *(uint4*)(smem + (OFF) + c * 128 + ((j * 16) ^ ((c & 7) << 4))) = PW2; } \
    { int g = t + 768; int c = g >> 3, j = g & 7;  *(uint4*)(smem + (OFF) + c * 128 + ((j * 16) ^ ((c & 7) << 4))) = PW3; } \
    { int g = t;       int e = g >> 4, q = g & 15; uint2 hv = { pk2bf(PZ0.x, PZ0.y), pk2bf(PZ0.z, PZ0.w) }; \
      *(uint2*)(smem + (OFF) + 16384 + e * 128 + ((q * 8) ^ ((e & 7) << 4))) = hv; } \
    { int g = t + 256; int e = g >> 4, q = g & 15; uint2 hv = { pk2bf(PZ1.x, PZ1.y), pk2bf(PZ1.z, PZ1.w) }; \
      *(uint2*)(smem + (OFF) + 16384 + e * 128 + ((q * 8) ^ ((e & 7) << 4))) = hv; } \
    { int g = t + 512; int e = g >> 4, q = g & 15; uint2 hv = { pk2bf(PZ2.x, PZ2.y), pk2bf(PZ2.z, PZ2.w) }; \
      *(uint2*)(smem + (OFF) + 16384 + e * 128 + ((q * 8) ^ ((e & 7) << 4))) = hv; } \
    { int g = t + 768; int e = g >> 4, q = g & 15; uint2 hv = { pk2bf(PZ3.x, PZ3.y), pk2bf(PZ3.z, PZ3.w) }; \
      *(uint2*)(smem + (OFF) + 16384 + e * 128 + ((q * 8) ^ ((e & 7) << 4))) = hv; } \
} while (0)
#define MMO(OFF) do { \
    _Pragma("unroll") \
    for (int ks = 0; ks < 2; ++ks) { \
        bf16x8 afr[2], bfr[4]; \
        int kb = ks * 64 + lg * 16; \
        _Pragma("unroll") \
        for (int cf = 0; cf < 2; ++cf) { \
            int c = w * 32 + cf * 16 + lr; \
            afr[cf] = *(const bf16x8*)(smem + (OFF) + c * 128 + (kb ^ ((c & 7) << 4))); \
        } \
        _Pragma("unroll") \
        for (int eb = 0; eb < 4; ++eb) { \
            int e = eb * 16 + lr; \
            bfr[eb] = *(const bf16x8*)(smem + (OFF) + 16384 + e * 128 + (kb ^ ((e & 7) << 4))); \
        } \
        _Pragma("unroll") \
        for (int cf = 0; cf < 2; ++cf) \
            _Pragma("unroll") \
            for (int eb = 0; eb < 4; ++eb) \
                acc[cf][eb] = __builtin_amdgcn_mfma_f32_16x16x32_bf16( \
                    afr[cf], bfr[eb], acc[cf][eb], 0, 0, 0); \
    } \
} while (0)

// ---------------- fallback: fused pretrans (all-atomic epilogue) ----------------
__global__ __launch_bounds__(256) void k_pretrans(
    const float* __restrict__ nf, const float* __restrict__ ef,
    const unsigned short* __restrict__ wpT, const float* __restrict__ bp,
    const int* __restrict__ src, const int* __restrict__ dst,
    const int* __restrict__ perm,
    float* s1, float* s2, float* mx, float* mn)
{
    __shared__ __align__(16) char smem[24576];
    __shared__ int pidx[64], sidx[64], didx[64];
    __shared__ int seg_start[65], seg_dst[64];
    __shared__ int nseg_s;
    __shared__ float sb[128];

    int t = threadIdx.x;
    int e0 = blockIdx.x * 64;
    if (t < 64) {
        int pe = perm[e0 + t];
        pidx[t] = pe; sidx[t] = src[pe]; didx[t] = dst[pe];
    }
    if (t < 128) sb[t] = bp[t];
    __syncthreads();

    int w  = t >> 6;
    int l  = t & 63;
    int lr = l & 15;
    int lg = l >> 4;

    f32x4 acc[2][4];
    #pragma unroll
    for (int i = 0; i < 2; ++i)
        #pragma unroll
        for (int j = 0; j < 4; ++j) acc[i][j] = (f32x4){0.f, 0.f, 0.f, 0.f};

    uint4  pw0, pw1, pw2, pw3;
    float4 pz0, pz1, pz2, pz3;

#define ZROW(NC, e) ((NC) < 2 ? nf + (size_t)sidx[e] * D : \
                     (NC) < 4 ? nf + (size_t)didx[e] * D : \
                                ef + (size_t)pidx[e] * D)
    PFN(0, pw0, pw1, pw2, pw3, pz0, pz1, pz2, pz3);
    WRN(0, pw0, pw1, pw2, pw3, pz0, pz1, pz2, pz3); PFN(1, pw0, pw1, pw2, pw3, pz0, pz1, pz2, pz3); __syncthreads(); MMO(0); __syncthreads();
    WRN(0, pw0, pw1, pw2, pw3, pz0, pz1, pz2, pz3); PFN(2, pw0, pw1, pw2, pw3, pz0, pz1, pz2, pz3); __syncthreads(); MMO(0); __syncthreads();
    WRN(0, pw0, pw1, pw2, pw3, pz0, pz1, pz2, pz3); PFN(3, pw0, pw1, pw2, pw3, pz0, pz1, pz2, pz3); __syncthreads(); MMO(0); __syncthreads();
    WRN(0, pw0, pw1, pw2, pw3, pz0, pz1, pz2, pz3); PFN(4, pw0, pw1, pw2, pw3, pz0, pz1, pz2, pz3); __syncthreads(); MMO(0); __syncthreads();
    WRN(0, pw0, pw1, pw2, pw3, pz0, pz1, pz2, pz3); PFN(5, pw0, pw1, pw2, pw3, pz0, pz1, pz2, pz3); __syncthreads(); MMO(0); __syncthreads();
    WRN(0, pw0, pw1, pw2, pw3, pz0, pz1, pz2, pz3);                                                 __syncthreads(); MMO(0); __syncthreads();
#undef ZROW

    #pragma unroll
    for (int cf = 0; cf < 2; ++cf)
        #pragma unroll
        for (int eb = 0; eb < 4; ++eb) {
            int e  = eb * 16 + lr;
            int c0 = w * 32 + cf * 16 + lg * 4;
            float v0 = fmaxf(acc[cf][eb][0] + sb[c0 + 0], 0.f);
            float v1 = fmaxf(acc[cf][eb][1] + sb[c0 + 1], 0.f);
            float v2 = fmaxf(acc[cf][eb][2] + sb[c0 + 2], 0.f);
            float v3 = fmaxf(acc[cf][eb][3] + sb[c0 + 3], 0.f);
            uint2 mv = { pk2bf(v0, v1), pk2bf(v2, v3) };
            *(uint2*)(smem + e * 256 + ((c0 * 2) ^ ((e & 7) << 4))) = mv;
        }
    if (t == 0) {
        int ns = 0;
        for (int e = 0; e < 64; ++e) {
            if (e == 0 || didx[e] != didx[e - 1]) { seg_dst[ns] = didx[e]; seg_start[ns] = e; ++ns; }
        }
        seg_start[ns] = 64; nseg_s = ns;
    }
    __syncthreads();
    int nseg = nseg_s;
    for (int idx = t; idx < nseg * D; idx += 256) {
        int sg = idx >> 7, c = idx & 127;
        int eb2 = seg_start[sg], ee = seg_start[sg + 1];
        float s = 0.f, q = 0.f, vmax = 0.f, vmin = __int_as_float(0x7f800000);
        for (int e = eb2; e < ee; ++e) {
            float v = bf2f(*(const unsigned short*)(smem + e * 256 + ((c * 2) ^ ((e & 7) << 4))));
            s += v; q += v * v;
            vmax = fmaxf(vmax, v); vmin = fminf(vmin, v);
        }
        size_t base = (size_t)seg_dst[sg] * D + c;
        atomicAdd(&s1[base], s);
        atomicAdd(&s2[base], q);
        atomicMax((int*)&mx[base], __float_as_int(vmax));
        atomicMin((int*)&mn[base], __float_as_int(vmin));
    }
}

#undef PFN
#undef WRN
#undef MMO

// ---------------- fallback: finalize in place + scalers ----------------
__global__ void k_finalize(float* s1, float* s2, float* mx, float* mn,
                           const int* __restrict__ hist, float* scal) {
    size_t idx = (size_t)blockIdx.x * blockDim.x + threadIdx.x;
    if (idx >= (size_t)N_NODES * D) return;
    int n = (int)(idx >> 7);
    int c = (int)(idx & 127);
    float dg = (float)hist[n];
    float ds = fmaxf(dg, 1.f);
    float m  = s1[idx] / ds;
    float var = fmaxf(s2[idx] / ds - m * m, 0.f);
    float sd  = sqrtf(var + EPS);
    bool nb = dg > 0.f;
    s1[idx] = m;
    mx[idx] = nb ? mx[idx] : 0.f;
    mn[idx] = nb ? mn[idx] : 0.f;
    s2[idx] = sd;
    if (c == 0) {
        float logd = logf(dg + 1.f);
        scal[2 * n]     = logd / AVG_D_LOG;
        scal[2 * n + 1] = AVG_D_LOG / fmaxf(logd, EPS);
    }
}

// ---------------- fused posttrans: out = relu(h@W1+b1)@W2 + b2 + nf ----------------
__global__ __launch_bounds__(256, 3) void k_post(
    const float* __restrict__ nf,
    const float* __restrict__ amean, const float* __restrict__ amax,
    const float* __restrict__ amin,  const float* __restrict__ astd,
    const float* __restrict__ scal,
    const unsigned short* __restrict__ w1T, const float* __restrict__ b1,
    const unsigned short* __restrict__ w2T, const float* __restrict__ b2,
    float* __restrict__ out)
{
    __shared__ __align__(16) char smem[49152];
    __shared__ float samp[64], satt[64], sb1[128], sb2[128];

    int t = threadIdx.x;
    int n0 = blockIdx.x * 64;
    if (t < 64) {
        int n = n0 + t;
        samp[t] = (n < N_NODES) ? scal[2 * n] : 0.f;
        satt[t] = (n < N_NODES) ? scal[2 * n + 1] : 0.f;
    }
    if (t < 128) { sb1[t] = b1[t]; sb2[t] = b2[t]; }
    __syncthreads();

    int w  = t >> 6, l = t & 63, lr = l & 15, lg = l >> 4;
    f32x4 acc[2][4];
    #pragma unroll
    for (int i = 0; i < 2; ++i)
        #pragma unroll
        for (int j = 0; j < 4; ++j) acc[i][j] = (f32x4){0.f, 0.f, 0.f, 0.f};

    for (int chunk = 0; chunk < 13; ++chunk) {
        #pragma unroll
        for (int p = 0; p < 8; ++p) {
            int g = t + 256 * p;
            int c = g >> 4, j = g & 15;
            uint4 wv = *(const uint4*)(w1T + (size_t)c * 1664 + chunk * 128 + j * 8);
            *(uint4*)(smem + c * 256 + ((j * 16) ^ ((c & 7) << 4))) = wv;
        }
        const float* base;
        int r;
        if (chunk == 0) { base = nf; r = 0; }
        else {
            int b = (chunk - 1) & 3;
            r = (chunk - 1) >> 2;
            base = (b == 0) ? amean : (b == 1) ? amax : (b == 2) ? amin : astd;
        }
        #pragma unroll
        for (int p = 0; p < 8; ++p) {
            int g = t + 256 * p;
            int e = g >> 5, q = g & 31;
            int n = n0 + e;
            float4 fv = {0.f, 0.f, 0.f, 0.f};
            if (n < N_NODES) {
                fv = *(const float4*)(base + (size_t)n * D + q * 4);
                if (r == 1) { float sc = samp[e]; fv.x *= sc; fv.y *= sc; fv.z *= sc; fv.w *= sc; }
                else if (r == 2) { float sc = satt[e]; fv.x *= sc; fv.y *= sc; fv.z *= sc; fv.w *= sc; }
            }
            uint2 hv = { pk2bf(fv.x, fv.y), pk2bf(fv.z, fv.w) };
            *(uint2*)(smem + 32768 + e * 256 + ((q * 8) ^ ((e & 7) << 4))) = hv;
        }
        __syncthreads();
        MM256(acc, 0, 32768);
        __syncthreads();
    }

    // h1 = relu(acc + b1) -> LDS B-layout @32768
    #pragma unroll
    for (int cf = 0; cf < 2; ++cf)
        #pragma unroll
        for (int eb = 0; eb < 4; ++eb) {
            int e  = eb * 16 + lr;
            int c0 = w * 32 + cf * 16 + lg * 4;
            float v0 = fmaxf(acc[cf][eb][0] + sb1[c0 + 0], 0.f);
            float v1 = fmaxf(acc[cf][eb][1] + sb1[c0 + 1], 0.f);
            float v2 = fmaxf(acc[cf][eb][2] + sb1[c0 + 2], 0.f);
            float v3 = fmaxf(acc[cf][eb][3] + sb1[c0 + 3], 0.f);
            uint2 hv = { pk2bf(v0, v1), pk2bf(v2, v3) };
            *(uint2*)(smem + 32768 + e * 256 + ((c0 * 2) ^ ((e & 7) << 4))) = hv;
        }
    #pragma unroll
    for (int p = 0; p < 8; ++p) {
        int g = t + 256 * p;
        int c = g >> 4, j = g & 15;
        uint4 wv = *(const uint4*)(w2T + (size_t)c * 128 + j * 8);
        *(uint4*)(smem + c * 256 + ((j * 16) ^ ((c & 7) << 4))) = wv;
    }
    __syncthreads();

    f32x4 acc2[2][4];
    #pragma unroll
    for (int i = 0; i < 2; ++i)
        #pragma unroll
        for (int j = 0; j < 4; ++j) acc2[i][j] = (f32x4){0.f, 0.f, 0.f, 0.f};
    MM256(acc2, 0, 32768);

    #pragma unroll
    for (int cf = 0; cf < 2; ++cf)
        #pragma unroll
        for (int eb = 0; eb < 4; ++eb) {
            int n = n0 + eb * 16 + lr;
            if (n < N_NODES) {
                int c0 = w * 32 + cf * 16 + lg * 4;
                float4 rv = *(const float4*)(nf + (size_t)n * D + c0);
                float4 ov = { acc2[cf][eb][0] + sb2[c0 + 0] + rv.x,
                              acc2[cf][eb][1] + sb2[c0 + 1] + rv.y,
                              acc2[cf][eb][2] + sb2[c0 + 2] + rv.z,
                              acc2[cf][eb][3] + sb2[c0 + 3] + rv.w };
                *(float4*)(out + (size_t)n * D + c0) = ov;
            }
        }
}

extern "C" void kernel_launch(void* const* d_in, const int* in_sizes, int n_in,
                              void* d_out, int out_size, void* d_ws, size_t ws_size,
                              hipStream_t stream) {
    const float* nf = (const float*)d_in[0];
    const float* ef = (const float*)d_in[1];
    const float* wp = (const float*)d_in[2];
    const float* bp = (const float*)d_in[3];
    const float* w1 = (const float*)d_in[4];
    const float* b1 = (const float*)d_in[5];
    const float* w2 = (const float*)d_in[6];
    const float* b2 = (const float*)d_in[7];
    const int* src  = (const int*)d_in[8];
    const int* dst  = (const int*)d_in[9];
    float* out = (float*)d_out;

    const size_t ND = (size_t)N_NODES * D;       // 6.4M
    const size_t MSG_SH = (size_t)N_EDGES * D;   // 102.4M ushorts
    char* wsb = (char*)d_ws;
    int*   hist   = (int*)wsb;                                   // 50048
    int*   cursor = hist + 50048;                                // 50048
    int*   perm   = cursor + 50048;                              // 800000
    int*   rnk    = perm + N_EDGES;                              // 800000
    unsigned short* wpT = (unsigned short*)(rnk + N_EDGES);      // 49152
    unsigned short* w1T = wpT + 49152;                           // 212992
    unsigned short* w2T = w1T + 212992;                          // 16384
    unsigned short* tail = w2T + 16384;

    // CSR layout
    unsigned short* p1   = tail;                 // ND bf16
    unsigned short* p2   = p1 + ND;              // ND bf16
    unsigned short* msgG = p2 + ND;              // MSG_SH bf16 (dst-sorted)
    float* s1   = (float*)(msgG + MSG_SH);
    float* s2   = s1 + ND;
    float* mx   = s2 + ND;
    float* mn   = mx + ND;
    float* scal = mn + ND;
    size_t need_csr = (size_t)((char*)(scal + 100096) - wsb);

    bool use_csr = ws_size >= need_csr;
    if (!use_csr) {
        s1   = (float*)tail;
        s2   = s1 + ND;
        mx   = s2 + ND;
        mn   = mx + ND;
        scal = mn + ND;
    }

    if (use_csr) {
        hipMemsetAsync(hist, 0, N_NODES * sizeof(int), stream);
    } else {
        hipLaunchKernelGGL(k_init, dim3(2048), dim3(256), 0, stream, hist, s1, s2, mx, mn);
    }
    hipLaunchKernelGGL(k_prep, dim3(1088 + (N_EDGES + 255) / 256), dim3(256), 0, stream,
                       wp, w1, w2, wpT, w1T, w2T, dst, hist);
    hipLaunchKernelGGL(k_scan, dim3(1), dim3(1024), 0, stream, hist, cursor);
    hipLaunchKernelGGL(k_scatter, dim3((N_EDGES + 255) / 256), dim3(256), 0, stream, dst, cursor, perm, rnk);
    if (use_csr) {
        hipLaunchKernelGGL(k_node, dim3((N_NODES + 63) / 64), dim3(256), 0, stream,
                           nf, wpT, bp, p1, p2);
        hipLaunchKernelGGL(k_edge, dim3(N_EDGES / 64), dim3(256), 0, stream,
                           ef, wpT, src, dst, rnk, p1, p2, msgG);
        hipLaunchKernelGGL(k_agg, dim3(N_NODES / 4), dim3(256), 0, stream,
                           msgG, cursor, hist, s1, s2, mx, mn, scal);
    } else {
        hipLaunchKernelGGL(k_pretrans, dim3(N_EDGES / 64), dim3(256), 0, stream,
                           nf, ef, wpT, bp, src, dst, perm, s1, s2, mx, mn);
        hipLaunchKernelGGL(k_finalize, dim3((unsigned)((ND + 255) / 256)), dim3(256), 0, stream,
                           s1, s2, mx, mn, hist, scal);
    }
    hipLaunchKernelGGL(k_post, dim3((N_NODES + 63) / 64), dim3(256), 0, stream,
                       nf, s1, mx, mn, s2, scal, w1T, b1, w2T, b2, out);
}

// Round 18
// 512.139 us; speedup vs baseline: 2.5161x; 1.0903x over previous
//
#include <hip/hip_runtime.h>
#include <math.h>

#define N_NODES 50000
#define N_EDGES 800000
#define D 128
#define AVG_D_LOG 2.833213344056216f  /* log(17.0) */
#define EPS 1e-5f

typedef __attribute__((ext_vector_type(8))) short bf16x8;
typedef __attribute__((ext_vector_type(4))) float f32x4;

__device__ __forceinline__ unsigned short f2bf(float x) {
    unsigned u = __float_as_uint(x);
    u += 0x7fffu + ((u >> 16) & 1u);
    return (unsigned short)(u >> 16);
}
__device__ __forceinline__ unsigned pk2bf(float a, float b) {
    return (unsigned)f2bf(a) | ((unsigned)f2bf(b) << 16);
}
__device__ __forceinline__ float bf2f(unsigned short u) {
    return __uint_as_float(((unsigned)u) << 16);
}

// ---------------- init (fallback only) ----------------
__global__ void k_init(int* hist, float* s1, float* s2, float* mx, float* mn) {
    size_t stride = (size_t)gridDim.x * blockDim.x;
    size_t i0 = (size_t)blockIdx.x * blockDim.x + threadIdx.x;
    const size_t ND4 = (size_t)N_NODES * D / 4;
    float4 z4 = {0.f, 0.f, 0.f, 0.f};
    int4 inf4 = {0x7f800000, 0x7f800000, 0x7f800000, 0x7f800000};
    for (size_t t = i0; t < ND4; t += stride) {
        ((float4*)s1)[t] = z4; ((float4*)s2)[t] = z4; ((float4*)mx)[t] = z4;
        ((int4*)mn)[t] = inf4;
    }
    for (size_t t = i0; t < N_NODES; t += stride) hist[t] = 0;
}

// ---------------- fused prep: 3 weight transposes + dst histogram + edge rank ----------
// rnk[e] = this edge's rank within its dst bucket (atomicAdd return value, free).
__global__ void k_prep(const float* __restrict__ wp, const float* __restrict__ w1,
                       const float* __restrict__ w2,
                       unsigned short* __restrict__ wpT, unsigned short* __restrict__ w1T,
                       unsigned short* __restrict__ w2T,
                       const int* __restrict__ dst, int* hist, int* rnk) {
    int b = blockIdx.x, t = threadIdx.x;
    if (b < 192) {
        int idx = b * 256 + t;
        int k = idx >> 7, c = idx & 127;
        wpT[(size_t)c * 384 + k] = f2bf(wp[idx]);
    } else if (b < 1024) {
        int idx = (b - 192) * 256 + t;
        int k = idx >> 7, c = idx & 127;
        w1T[(size_t)c * 1664 + k] = f2bf(w1[idx]);
    } else if (b < 1088) {
        int idx = (b - 1024) * 256 + t;
        int k = idx >> 7, c = idx & 127;
        w2T[(size_t)c * 128 + k] = f2bf(w2[idx]);
    } else {
        int e = (b - 1088) * 256 + t;
        if (e < N_EDGES) rnk[e] = atomicAdd(&hist[dst[e]], 1);
    }
}

// ---------------- parallel exclusive scan: cursor[n] = row START of node n ------------
__global__ __launch_bounds__(1024) void k_scan(const int* __restrict__ hist, int* cursor) {
    __shared__ int part[1024];
    int t = threadIdx.x;
    const int chunk = (N_NODES + 1023) / 1024;
    int lo = t * chunk;
    int hi = lo + chunk; if (hi > N_NODES) hi = N_NODES;
    int s = 0;
    for (int i = lo; i < hi; ++i) s += hist[i];
    part[t] = s;
    __syncthreads();
    for (int off = 1; off < 1024; off <<= 1) {
        int v = (t >= off) ? part[t - off] : 0;
        __syncthreads();
        part[t] += v;
        __syncthreads();
    }
    int run = (t == 0) ? 0 : part[t - 1];
    for (int i = lo; i < hi; ++i) { cursor[i] = run; run += hist[i]; }
}

// fallback only: build perm (mutates a scratch copy of cursor semantics via atomics)
__global__ void k_scatter_fb(const int* __restrict__ dst, int* curs2, int* perm) {
    int e = blockIdx.x * blockDim.x + threadIdx.x;
    if (e < N_EDGES) {
        int pos = atomicAdd(&curs2[dst[e]], 1);
        perm[pos] = e;
    }
}
__global__ void k_copy_cursor(const int* __restrict__ cursor, int* curs2) {
    int i = blockIdx.x * blockDim.x + threadIdx.x;
    if (i < N_NODES) curs2[i] = cursor[i];
}

// ---- 256B-row-stride MFMA macro (K=128 tiles) ----
#define MM256(ACC, AOFF, BOFF) do { \
    _Pragma("unroll") \
    for (int ks = 0; ks < 4; ++ks) { \
        bf16x8 afr[2], bfr[4]; \
        int kb = ks * 64 + lg * 16; \
        _Pragma("unroll") \
        for (int cf = 0; cf < 2; ++cf) { \
            int c = w * 32 + cf * 16 + lr; \
            afr[cf] = *(const bf16x8*)(smem + (AOFF) + c * 256 + (kb ^ ((c & 7) << 4))); \
        } \
        _Pragma("unroll") \
        for (int eb = 0; eb < 4; ++eb) { \
            int e = eb * 16 + lr; \
            bfr[eb] = *(const bf16x8*)(smem + (BOFF) + e * 256 + (kb ^ ((e & 7) << 4))); \
        } \
        _Pragma("unroll") \
        for (int cf = 0; cf < 2; ++cf) \
            _Pragma("unroll") \
            for (int eb = 0; eb < 4; ++eb) \
                ACC[cf][eb] = __builtin_amdgcn_mfma_f32_16x16x32_bf16( \
                    afr[cf], bfr[eb], ACC[cf][eb], 0, 0, 0); \
    } \
} while (0)

// ---------------- k_node: P1 = nf@Ws, P2 = nf@Wd + b (bf16 out) ----------------
__global__ __launch_bounds__(256) void k_node(
    const float* __restrict__ nf, const unsigned short* __restrict__ wpT,
    const float* __restrict__ bp,
    unsigned short* __restrict__ p1, unsigned short* __restrict__ p2)
{
    __shared__ __align__(16) char smem[49152];
    __shared__ float sb[128];
    int t = threadIdx.x;
    int n0 = blockIdx.x * 64;
    if (t < 128) sb[t] = bp[t];
    int w = t >> 6, l = t & 63, lr = l & 15, lg = l >> 4;

    f32x4 acc1[2][4], acc2[2][4];
    #pragma unroll
    for (int i = 0; i < 2; ++i)
        #pragma unroll
        for (int j = 0; j < 4; ++j) { acc1[i][j] = (f32x4){0.f,0.f,0.f,0.f}; acc2[i][j] = (f32x4){0.f,0.f,0.f,0.f}; }

    #pragma unroll
    for (int p = 0; p < 8; ++p) {
        int g = t + 256 * p;
        int e = g >> 5, q = g & 31;
        int n = n0 + e;
        float4 fv = {0.f, 0.f, 0.f, 0.f};
        if (n < N_NODES) fv = *(const float4*)(nf + (size_t)n * D + q * 4);
        uint2 hv = { pk2bf(fv.x, fv.y), pk2bf(fv.z, fv.w) };
        *(uint2*)(smem + 32768 + e * 256 + ((q * 8) ^ ((e & 7) << 4))) = hv;
    }
    #pragma unroll
    for (int p = 0; p < 8; ++p) {
        int g = t + 256 * p;
        int c = g >> 4, j = g & 15;
        uint4 wv = *(const uint4*)(wpT + (size_t)c * 384 + j * 8);
        *(uint4*)(smem + c * 256 + ((j * 16) ^ ((c & 7) << 4))) = wv;
    }
    __syncthreads();
    MM256(acc1, 0, 32768);
    __syncthreads();
    #pragma unroll
    for (int p = 0; p < 8; ++p) {
        int g = t + 256 * p;
        int c = g >> 4, j = g & 15;
        uint4 wv = *(const uint4*)(wpT + (size_t)c * 384 + 128 + j * 8);
        *(uint4*)(smem + c * 256 + ((j * 16) ^ ((c & 7) << 4))) = wv;
    }
    __syncthreads();
    MM256(acc2, 0, 32768);
    __syncthreads();

    #pragma unroll
    for (int cf = 0; cf < 2; ++cf)
        #pragma unroll
        for (int eb = 0; eb < 4; ++eb) {
            int e  = eb * 16 + lr;
            int c0 = w * 32 + cf * 16 + lg * 4;
            uint2 v1 = { pk2bf(acc1[cf][eb][0], acc1[cf][eb][1]),
                         pk2bf(acc1[cf][eb][2], acc1[cf][eb][3]) };
            *(uint2*)(smem + e * 256 + ((c0 * 2) ^ ((e & 7) << 4))) = v1;
            uint2 v2 = { pk2bf(acc2[cf][eb][0] + sb[c0 + 0], acc2[cf][eb][1] + sb[c0 + 1]),
                         pk2bf(acc2[cf][eb][2] + sb[c0 + 2], acc2[cf][eb][3] + sb[c0 + 3]) };
            *(uint2*)(smem + 16384 + e * 256 + ((c0 * 2) ^ ((e & 7) << 4))) = v2;
        }
    __syncthreads();
    #pragma unroll
    for (int p = 0; p < 4; ++p) {
        int e = (t >> 4) + p * 16;
        int q = t & 15;
        int n = n0 + e;
        if (n < N_NODES) {
            int qq = q ^ (e & 7);
            uint4 v1 = *(const uint4*)(smem + e * 256 + q * 16);
            *(uint4*)(p1 + (size_t)n * D + qq * 8) = v1;
            uint4 v2 = *(const uint4*)(smem + 16384 + e * 256 + q * 16);
            *(uint4*)(p2 + (size_t)n * D + qq * 8) = v2;
        }
    }
}

// ---------------- k_edge: pos = cursor[dst] + rnk (no scatter kernel needed) -----------
// E = ef@We (ef sequential); msg = relu(E + P1[src] + P2[dst]);
// copy-out writes each msg row to its dst-sorted position (unique -> race-free).
__global__ __launch_bounds__(256) void k_edge(
    const float* __restrict__ ef, const unsigned short* __restrict__ wpT,
    const int* __restrict__ src, const int* __restrict__ dst,
    const int* __restrict__ cursor, const int* __restrict__ rnk,
    const unsigned short* __restrict__ p1, const unsigned short* __restrict__ p2,
    unsigned short* __restrict__ msgG)
{
    __shared__ __align__(16) char smem[49152];
    __shared__ int sidx[64], didx[64], ridx[64];

    int t = threadIdx.x;
    int e0 = blockIdx.x * 64;
    if (t < 64) {
        int d = dst[e0 + t];
        sidx[t] = src[e0 + t];
        didx[t] = d;
        ridx[t] = cursor[d] + rnk[e0 + t];
    }
    int w = t >> 6, l = t & 63, lr = l & 15, lg = l >> 4;

    f32x4 acc[2][4];
    #pragma unroll
    for (int i = 0; i < 2; ++i)
        #pragma unroll
        for (int j = 0; j < 4; ++j) acc[i][j] = (f32x4){0.f, 0.f, 0.f, 0.f};

    // stage We (k 256..383) @0
    #pragma unroll
    for (int p = 0; p < 8; ++p) {
        int g = t + 256 * p;
        int c = g >> 4, j = g & 15;
        uint4 wv = *(const uint4*)(wpT + (size_t)c * 384 + 256 + j * 8);
        *(uint4*)(smem + c * 256 + ((j * 16) ^ ((c & 7) << 4))) = wv;
    }
    // stage z = ef rows (SEQUENTIAL) @32768
    #pragma unroll
    for (int p = 0; p < 8; ++p) {
        int g = t + 256 * p;
        int e = g >> 5, q = g & 31;
        float4 fv = *(const float4*)(ef + (size_t)(e0 + e) * D + q * 4);
        uint2 hv = { pk2bf(fv.x, fv.y), pk2bf(fv.z, fv.w) };
        *(uint2*)(smem + 32768 + e * 256 + ((q * 8) ^ ((e & 7) << 4))) = hv;
    }
    __syncthreads();   // also publishes sidx/didx/ridx
    MM256(acc, 0, 32768);
    __syncthreads();
    // stage P1[src] @0, P2[dst] @16384 (coalesced 16B over L3-resident arrays)
    #pragma unroll
    for (int p = 0; p < 4; ++p) {
        int g = t + 256 * p;
        int e = g >> 4, q = g & 15;
        uint4 v1 = *(const uint4*)(p1 + (size_t)sidx[e] * D + q * 8);
        *(uint4*)(smem + e * 256 + ((q * 16) ^ ((e & 7) << 4))) = v1;
        uint4 v2 = *(const uint4*)(p2 + (size_t)didx[e] * D + q * 8);
        *(uint4*)(smem + 16384 + e * 256 + ((q * 16) ^ ((e & 7) << 4))) = v2;
    }
    __syncthreads();
    // epilogue: msg = relu(E + P1s + P2d) -> msg tile @32768
    #pragma unroll
    for (int cf = 0; cf < 2; ++cf)
        #pragma unroll
        for (int eb = 0; eb < 4; ++eb) {
            int e  = eb * 16 + lr;
            int c0 = w * 32 + cf * 16 + lg * 4;
            uint2 a1 = *(const uint2*)(smem + e * 256 + ((c0 * 2) ^ ((e & 7) << 4)));
            uint2 a2 = *(const uint2*)(smem + 16384 + e * 256 + ((c0 * 2) ^ ((e & 7) << 4)));
            float v0 = acc[cf][eb][0] + bf2f((unsigned short)(a1.x & 0xffff)) + bf2f((unsigned short)(a2.x & 0xffff));
            float v1 = acc[cf][eb][1] + bf2f((unsigned short)(a1.x >> 16))    + bf2f((unsigned short)(a2.x >> 16));
            float v2 = acc[cf][eb][2] + bf2f((unsigned short)(a1.y & 0xffff)) + bf2f((unsigned short)(a2.y & 0xffff));
            float v3 = acc[cf][eb][3] + bf2f((unsigned short)(a1.y >> 16))    + bf2f((unsigned short)(a2.y >> 16));
            uint2 mv = { pk2bf(fmaxf(v0, 0.f), fmaxf(v1, 0.f)),
                         pk2bf(fmaxf(v2, 0.f), fmaxf(v3, 0.f)) };
            *(uint2*)(smem + 32768 + e * 256 + ((c0 * 2) ^ ((e & 7) << 4))) = mv;
        }
    __syncthreads();
    // copy-out to dst-sorted positions (scattered 256B-row writes, fire-and-forget)
    #pragma unroll
    for (int p = 0; p < 4; ++p) {
        int e = (t >> 4) + p * 16;
        int q = t & 15;
        uint4 v = *(const uint4*)(smem + 32768 + e * 256 + q * 16);
        int qq = q ^ (e & 7);
        *(uint4*)(msgG + (size_t)ridx[e] * D + qq * 8) = v;
    }
}

// ---------------- k_agg: SEQUENTIAL msgG rows (dst-sorted) -> fp32 aggregates ----------
__global__ __launch_bounds__(256) void k_agg(
    const unsigned short* __restrict__ msgG,
    const int* __restrict__ cursor, const int* __restrict__ hist,
    float* __restrict__ s1, float* __restrict__ s2,
    float* __restrict__ mx, float* __restrict__ mn, float* __restrict__ scal)
{
    int t = threadIdx.x;
    int n = blockIdx.x * 4 + (t >> 6);
    int tl = t & 63;
    int deg = hist[n];
    int rs  = cursor[n];          // cursor holds row STARTS (never mutated in CSR path)

    float sum0 = 0.f, sum1 = 0.f, sq0 = 0.f, sq1 = 0.f;
    float mx0 = -3.402823e38f, mx1 = -3.402823e38f;
    float mn0 =  3.402823e38f, mn1 =  3.402823e38f;
    const uint* mg = (const uint*)msgG;
    for (int e = 0; e < deg; ++e) {
        uint v = mg[(size_t)(rs + e) * 64 + tl];
        float a = bf2f((unsigned short)(v & 0xffff));
        float b = bf2f((unsigned short)(v >> 16));
        sum0 += a; sum1 += b; sq0 += a * a; sq1 += b * b;
        mx0 = fmaxf(mx0, a); mx1 = fmaxf(mx1, b);
        mn0 = fminf(mn0, a); mn1 = fminf(mn1, b);
    }
    float dg = (float)deg;
    float ds = fmaxf(dg, 1.f);
    bool nb = deg > 0;
    float m0 = sum0 / ds, m1 = sum1 / ds;
    float sd0 = sqrtf(fmaxf(sq0 / ds - m0 * m0, 0.f) + EPS);
    float sd1 = sqrtf(fmaxf(sq1 / ds - m1 * m1, 0.f) + EPS);
    size_t base = (size_t)n * D + tl * 2;
    *(float2*)&s1[base] = (float2){m0, m1};
    *(float2*)&s2[base] = (float2){sd0, sd1};
    *(float2*)&mx[base] = (float2){nb ? mx0 : 0.f, nb ? mx1 : 0.f};
    *(float2*)&mn[base] = (float2){nb ? mn0 : 0.f, nb ? mn1 : 0.f};
    if (tl == 0) {
        float logd = logf(dg + 1.f);
        scal[2 * n]     = logd / AVG_D_LOG;
        scal[2 * n + 1] = AVG_D_LOG / fmaxf(logd, EPS);
    }
}

// staging macros for the fallback fused pretrans
#define PFN(NC, PW0, PW1, PW2, PW3, PZ0, PZ1, PZ2, PZ3) do { \
    { int g = t;       int c = g >> 3, j = g & 7;  PW0 = *(const uint4*)(wpT + (size_t)c * 384 + (NC) * 64 + j * 8); } \
    { int g = t + 256; int c = g >> 3, j = g & 7;  PW1 = *(const uint4*)(wpT + (size_t)c * 384 + (NC) * 64 + j * 8); } \
    { int g = t + 512; int c = g >> 3, j = g & 7;  PW2 = *(const uint4*)(wpT + (size_t)c * 384 + (NC) * 64 + j * 8); } \
    { int g = t + 768; int c = g >> 3, j = g & 7;  PW3 = *(const uint4*)(wpT + (size_t)c * 384 + (NC) * 64 + j * 8); } \
    { int g = t;       int e = g >> 4, q = g & 15; PZ0 = *(const float4*)(ZROW(NC, e) + (((NC) & 1) * 64) + q * 4); } \
    { int g = t + 256; int e = g >> 4, q = g & 15; PZ1 = *(const float4*)(ZROW(NC, e) + (((NC) & 1) * 64) + q * 4); } \
    { int g = t + 512; int e = g >> 4, q = g & 15; PZ2 = *(const float4*)(ZROW(NC, e) + (((NC) & 1) * 64) + q * 4); } \
    { int g = t + 768; int e = g >> 4, q = g & 15; PZ3 = *(const float4*)(ZROW(NC, e) + (((NC) & 1) * 64) + q * 4); } \
} while (0)
#define WRN(OFF, PW0, PW1, PW2, PW3, PZ0, PZ1, PZ2, PZ3) do { \
    { int g = t;       int c = g >> 3, j = g & 7;  *(uint4*)(smem + (OFF) + c * 128 + ((j * 16) ^ ((c & 7) << 4))) = PW0; } \
    { int g = t + 256; int c = g >> 3, j = g & 7;  *(uint4*)(smem + (OFF) + c * 128 + ((j * 16) ^ ((c & 7) << 4))) = PW1; } \
    { int g = t + 512; int c = g >> 3, j = g & 7;  *(uint4*)(smem + (OFF) + c * 128 + ((j * 16) ^ ((c & 7) << 4))) = PW2; } \
    { int g = t + 768; int c = g >> 3, j = g & 7;  *(uint4*)(smem + (OFF) + c * 128 + ((j * 16) ^ ((c & 7) << 4))) = PW3; } \
    { int g = t;       int e = g >> 4, q = g & 15; uint2 hv = { pk2bf(PZ0.x, PZ0.y), pk2bf(PZ0.z, PZ0.w) }; \
      *(uint2*)(smem + (OFF) + 16384 + e * 128 + ((q * 8) ^ ((e & 7) << 4))) = hv; } \
    { int g = t + 256; int e = g >> 4, q = g & 15; uint2 hv = { pk2bf(PZ1.x, PZ1.y), pk2bf(PZ1.z, PZ1.w) }; \
      *(uint2*)(smem + (OFF) + 16384 + e * 128 + ((q * 8) ^ ((e & 7) << 4))) = hv; } \
    { int g = t + 512; int e = g >> 4, q = g & 15; uint2 hv = { pk2bf(PZ2.x, PZ2.y), pk2bf(PZ2.z, PZ2.w) }; \
      *(uint2*)(smem + (OFF) + 16384 + e * 128 + ((q * 8) ^ ((e & 7) << 4))) = hv; } \
    { int g = t + 768; int e = g >> 4, q = g & 15; uint2 hv = { pk2bf(PZ3.x, PZ3.y), pk2bf(PZ3.z, PZ3.w) }; \
      *(uint2*)(smem + (OFF) + 16384 + e * 128 + ((q * 8) ^ ((e & 7) << 4))) = hv; } \
} while (0)
#define MMO(OFF) do { \
    _Pragma("unroll") \
    for (int ks = 0; ks < 2; ++ks) { \
        bf16x8 afr[2], bfr[4]; \
        int kb = ks * 64 + lg * 16; \
        _Pragma("unroll") \
        for (int cf = 0; cf < 2; ++cf) { \
            int c = w * 32 + cf * 16 + lr; \
            afr[cf] = *(const bf16x8*)(smem + (OFF) + c * 128 + (kb ^ ((c & 7) << 4))); \
        } \
        _Pragma("unroll") \
        for (int eb = 0; eb < 4; ++eb) { \
            int e = eb * 16 + lr; \
            bfr[eb] = *(const bf16x8*)(smem + (OFF) + 16384 + e * 128 + (kb ^ ((e & 7) << 4))); \
        } \
        _Pragma("unroll") \
        for (int cf = 0; cf < 2; ++cf) \
            _Pragma("unroll") \
            for (int eb = 0; eb < 4; ++eb) \
                acc[cf][eb] = __builtin_amdgcn_mfma_f32_16x16x32_bf16( \
                    afr[cf], bfr[eb], acc[cf][eb], 0, 0, 0); \
    } \
} while (0)

// ---------------- fallback: fused pretrans (all-atomic epilogue) ----------------
__global__ __launch_bounds__(256) void k_pretrans(
    const float* __restrict__ nf, const float* __restrict__ ef,
    const unsigned short* __restrict__ wpT, const float* __restrict__ bp,
    const int* __restrict__ src, const int* __restrict__ dst,
    const int* __restrict__ perm,
    float* s1, float* s2, float* mx, float* mn)
{
    __shared__ __align__(16) char smem[24576];
    __shared__ int pidx[64], sidx[64], didx[64];
    __shared__ int seg_start[65], seg_dst[64];
    __shared__ int nseg_s;
    __shared__ float sb[128];

    int t = threadIdx.x;
    int e0 = blockIdx.x * 64;
    if (t < 64) {
        int pe = perm[e0 + t];
        pidx[t] = pe; sidx[t] = src[pe]; didx[t] = dst[pe];
    }
    if (t < 128) sb[t] = bp[t];
    __syncthreads();

    int w  = t >> 6;
    int l  = t & 63;
    int lr = l & 15;
    int lg = l >> 4;

    f32x4 acc[2][4];
    #pragma unroll
    for (int i = 0; i < 2; ++i)
        #pragma unroll
        for (int j = 0; j < 4; ++j) acc[i][j] = (f32x4){0.f, 0.f, 0.f, 0.f};

    uint4  pw0, pw1, pw2, pw3;
    float4 pz0, pz1, pz2, pz3;

#define ZROW(NC, e) ((NC) < 2 ? nf + (size_t)sidx[e] * D : \
                     (NC) < 4 ? nf + (size_t)didx[e] * D : \
                                ef + (size_t)pidx[e] * D)
    PFN(0, pw0, pw1, pw2, pw3, pz0, pz1, pz2, pz3);
    WRN(0, pw0, pw1, pw2, pw3, pz0, pz1, pz2, pz3); PFN(1, pw0, pw1, pw2, pw3, pz0, pz1, pz2, pz3); __syncthreads(); MMO(0); __syncthreads();
    WRN(0, pw0, pw1, pw2, pw3, pz0, pz1, pz2, pz3); PFN(2, pw0, pw1, pw2, pw3, pz0, pz1, pz2, pz3); __syncthreads(); MMO(0); __syncthreads();
    WRN(0, pw0, pw1, pw2, pw3, pz0, pz1, pz2, pz3); PFN(3, pw0, pw1, pw2, pw3, pz0, pz1, pz2, pz3); __syncthreads(); MMO(0); __syncthreads();
    WRN(0, pw0, pw1, pw2, pw3, pz0, pz1, pz2, pz3); PFN(4, pw0, pw1, pw2, pw3, pz0, pz1, pz2, pz3); __syncthreads(); MMO(0); __syncthreads();
    WRN(0, pw0, pw1, pw2, pw3, pz0, pz1, pz2, pz3); PFN(5, pw0, pw1, pw2, pw3, pz0, pz1, pz2, pz3); __syncthreads(); MMO(0); __syncthreads();
    WRN(0, pw0, pw1, pw2, pw3, pz0, pz1, pz2, pz3);                                                 __syncthreads(); MMO(0); __syncthreads();
#undef ZROW

    #pragma unroll
    for (int cf = 0; cf < 2; ++cf)
        #pragma unroll
        for (int eb = 0; eb < 4; ++eb) {
            int e  = eb * 16 + lr;
            int c0 = w * 32 + cf * 16 + lg * 4;
            float v0 = fmaxf(acc[cf][eb][0] + sb[c0 + 0], 0.f);
            float v1 = fmaxf(acc[cf][eb][1] + sb[c0 + 1], 0.f);
            float v2 = fmaxf(acc[cf][eb][2] + sb[c0 + 2], 0.f);
            float v3 = fmaxf(acc[cf][eb][3] + sb[c0 + 3], 0.f);
            uint2 mv = { pk2bf(v0, v1), pk2bf(v2, v3) };
            *(uint2*)(smem + e * 256 + ((c0 * 2) ^ ((e & 7) << 4))) = mv;
        }
    if (t == 0) {
        int ns = 0;
        for (int e = 0; e < 64; ++e) {
            if (e == 0 || didx[e] != didx[e - 1]) { seg_dst[ns] = didx[e]; seg_start[ns] = e; ++ns; }
        }
        seg_start[ns] = 64; nseg_s = ns;
    }
    __syncthreads();
    int nseg = nseg_s;
    for (int idx = t; idx < nseg * D; idx += 256) {
        int sg = idx >> 7, c = idx & 127;
        int eb2 = seg_start[sg], ee = seg_start[sg + 1];
        float s = 0.f, q = 0.f, vmax = 0.f, vmin = __int_as_float(0x7f800000);
        for (int e = eb2; e < ee; ++e) {
            float v = bf2f(*(const unsigned short*)(smem + e * 256 + ((c * 2) ^ ((e & 7) << 4))));
            s += v; q += v * v;
            vmax = fmaxf(vmax, v); vmin = fminf(vmin, v);
        }
        size_t base = (size_t)seg_dst[sg] * D + c;
        atomicAdd(&s1[base], s);
        atomicAdd(&s2[base], q);
        atomicMax((int*)&mx[base], __float_as_int(vmax));
        atomicMin((int*)&mn[base], __float_as_int(vmin));
    }
}

#undef PFN
#undef WRN
#undef MMO

// ---------------- fallback: finalize in place + scalers ----------------
__global__ void k_finalize(float* s1, float* s2, float* mx, float* mn,
                           const int* __restrict__ hist, float* scal) {
    size_t idx = (size_t)blockIdx.x * blockDim.x + threadIdx.x;
    if (idx >= (size_t)N_NODES * D) return;
    int n = (int)(idx >> 7);
    int c = (int)(idx & 127);
    float dg = (float)hist[n];
    float ds = fmaxf(dg, 1.f);
    float m  = s1[idx] / ds;
    float var = fmaxf(s2[idx] / ds - m * m, 0.f);
    float sd  = sqrtf(var + EPS);
    bool nb = dg > 0.f;
    s1[idx] = m;
    mx[idx] = nb ? mx[idx] : 0.f;
    mn[idx] = nb ? mn[idx] : 0.f;
    s2[idx] = sd;
    if (c == 0) {
        float logd = logf(dg + 1.f);
        scal[2 * n]     = logd / AVG_D_LOG;
        scal[2 * n + 1] = AVG_D_LOG / fmaxf(logd, EPS);
    }
}

// ---------------- fused posttrans: out = relu(h@W1+b1)@W2 + b2 + nf ----------------
__global__ __launch_bounds__(256, 3) void k_post(
    const float* __restrict__ nf,
    const float* __restrict__ amean, const float* __restrict__ amax,
    const float* __restrict__ amin,  const float* __restrict__ astd,
    const float* __restrict__ scal,
    const unsigned short* __restrict__ w1T, const float* __restrict__ b1,
    const unsigned short* __restrict__ w2T, const float* __restrict__ b2,
    float* __restrict__ out)
{
    __shared__ __align__(16) char smem[49152];
    __shared__ float samp[64], satt[64], sb1[128], sb2[128];

    int t = threadIdx.x;
    int n0 = blockIdx.x * 64;
    if (t < 64) {
        int n = n0 + t;
        samp[t] = (n < N_NODES) ? scal[2 * n] : 0.f;
        satt[t] = (n < N_NODES) ? scal[2 * n + 1] : 0.f;
    }
    if (t < 128) { sb1[t] = b1[t]; sb2[t] = b2[t]; }
    __syncthreads();

    int w  = t >> 6, l = t & 63, lr = l & 15, lg = l >> 4;
    f32x4 acc[2][4];
    #pragma unroll
    for (int i = 0; i < 2; ++i)
        #pragma unroll
        for (int j = 0; j < 4; ++j) acc[i][j] = (f32x4){0.f, 0.f, 0.f, 0.f};

    for (int chunk = 0; chunk < 13; ++chunk) {
        #pragma unroll
        for (int p = 0; p < 8; ++p) {
            int g = t + 256 * p;
            int c = g >> 4, j = g & 15;
            uint4 wv = *(const uint4*)(w1T + (size_t)c * 1664 + chunk * 128 + j * 8);
            *(uint4*)(smem + c * 256 + ((j * 16) ^ ((c & 7) << 4))) = wv;
        }
        const float* base;
        int r;
        if (chunk == 0) { base = nf; r = 0; }
        else {
            int b = (chunk - 1) & 3;
            r = (chunk - 1) >> 2;
            base = (b == 0) ? amean : (b == 1) ? amax : (b == 2) ? amin : astd;
        }
        #pragma unroll
        for (int p = 0; p < 8; ++p) {
            int g = t + 256 * p;
            int e = g >> 5, q = g & 31;
            int n = n0 + e;
            float4 fv = {0.f, 0.f, 0.f, 0.f};
            if (n < N_NODES) {
                fv = *(const float4*)(base + (size_t)n * D + q * 4);
                if (r == 1) { float sc = samp[e]; fv.x *= sc; fv.y *= sc; fv.z *= sc; fv.w *= sc; }
                else if (r == 2) { float sc = satt[e]; fv.x *= sc; fv.y *= sc; fv.z *= sc; fv.w *= sc; }
            }
            uint2 hv = { pk2bf(fv.x, fv.y), pk2bf(fv.z, fv.w) };
            *(uint2*)(smem + 32768 + e * 256 + ((q * 8) ^ ((e & 7) << 4))) = hv;
        }
        __syncthreads();
        MM256(acc, 0, 32768);
        __syncthreads();
    }

    // h1 = relu(acc + b1) -> LDS B-layout @32768
    #pragma unroll
    for (int cf = 0; cf < 2; ++cf)
        #pragma unroll
        for (int eb = 0; eb < 4; ++eb) {
            int e  = eb * 16 + lr;
            int c0 = w * 32 + cf * 16 + lg * 4;
            float v0 = fmaxf(acc[cf][eb][0] + sb1[c0 + 0], 0.f);
            float v1 = fmaxf(acc[cf][eb][1] + sb1[c0 + 1], 0.f);
            float v2 = fmaxf(acc[cf][eb][2] + sb1[c0 + 2], 0.f);
            float v3 = fmaxf(acc[cf][eb][3] + sb1[c0 + 3], 0.f);
            uint2 hv = { pk2bf(v0, v1), pk2bf(v2, v3) };
            *(uint2*)(smem + 32768 + e * 256 + ((c0 * 2) ^ ((e & 7) << 4))) = hv;
        }
    #pragma unroll
    for (int p = 0; p < 8; ++p) {
        int g = t + 256 * p;
        int c = g >> 4, j = g & 15;
        uint4 wv = *(const uint4*)(w2T + (size_t)c * 128 + j * 8);
        *(uint4*)(smem + c * 256 + ((j * 16) ^ ((c & 7) << 4))) = wv;
    }
    __syncthreads();

    f32x4 acc2[2][4];
    #pragma unroll
    for (int i = 0; i < 2; ++i)
        #pragma unroll
        for (int j = 0; j < 4; ++j) acc2[i][j] = (f32x4){0.f, 0.f, 0.f, 0.f};
    MM256(acc2, 0, 32768);

    #pragma unroll
    for (int cf = 0; cf < 2; ++cf)
        #pragma unroll
        for (int eb = 0; eb < 4; ++eb) {
            int n = n0 + eb * 16 + lr;
            if (n < N_NODES) {
                int c0 = w * 32 + cf * 16 + lg * 4;
                float4 rv = *(const float4*)(nf + (size_t)n * D + c0);
                float4 ov = { acc2[cf][eb][0] + sb2[c0 + 0] + rv.x,
                              acc2[cf][eb][1] + sb2[c0 + 1] + rv.y,
                              acc2[cf][eb][2] + sb2[c0 + 2] + rv.z,
                              acc2[cf][eb][3] + sb2[c0 + 3] + rv.w };
                *(float4*)(out + (size_t)n * D + c0) = ov;
            }
        }
}

extern "C" void kernel_launch(void* const* d_in, const int* in_sizes, int n_in,
                              void* d_out, int out_size, void* d_ws, size_t ws_size,
                              hipStream_t stream) {
    const float* nf = (const float*)d_in[0];
    const float* ef = (const float*)d_in[1];
    const float* wp = (const float*)d_in[2];
    const float* bp = (const float*)d_in[3];
    const float* w1 = (const float*)d_in[4];
    const float* b1 = (const float*)d_in[5];
    const float* w2 = (const float*)d_in[6];
    const float* b2 = (const float*)d_in[7];
    const int* src  = (const int*)d_in[8];
    const int* dst  = (const int*)d_in[9];
    float* out = (float*)d_out;

    const size_t ND = (size_t)N_NODES * D;       // 6.4M
    const size_t MSG_SH = (size_t)N_EDGES * D;   // 102.4M ushorts
    char* wsb = (char*)d_ws;
    int*   hist   = (int*)wsb;                                   // 50048
    int*   cursor = hist + 50048;                                // 50048 (row starts)
    int*   curs2  = cursor + 50048;                              // 50048 (fallback scratch)
    int*   perm   = curs2 + 50048;                               // 800000 (fallback only)
    int*   rnk    = perm + N_EDGES;                              // 800000
    unsigned short* wpT = (unsigned short*)(rnk + N_EDGES);      // 49152
    unsigned short* w1T = wpT + 49152;                           // 212992
    unsigned short* w2T = w1T + 212992;                          // 16384
    unsigned short* tail = w2T + 16384;

    // CSR layout
    unsigned short* p1   = tail;                 // ND bf16
    unsigned short* p2   = p1 + ND;              // ND bf16
    unsigned short* msgG = p2 + ND;              // MSG_SH bf16 (dst-sorted)
    float* s1   = (float*)(msgG + MSG_SH);
    float* s2   = s1 + ND;
    float* mx   = s2 + ND;
    float* mn   = mx + ND;
    float* scal = mn + ND;
    size_t need_csr = (size_t)((char*)(scal + 100096) - wsb);

    bool use_csr = ws_size >= need_csr;
    if (!use_csr) {
        s1   = (float*)tail;
        s2   = s1 + ND;
        mx   = s2 + ND;
        mn   = mx + ND;
        scal = mn + ND;
    }

    if (use_csr) {
        hipMemsetAsync(hist, 0, N_NODES * sizeof(int), stream);
    } else {
        hipLaunchKernelGGL(k_init, dim3(2048), dim3(256), 0, stream, hist, s1, s2, mx, mn);
    }
    hipLaunchKernelGGL(k_prep, dim3(1088 + (N_EDGES + 255) / 256), dim3(256), 0, stream,
                       wp, w1, w2, wpT, w1T, w2T, dst, hist, rnk);
    hipLaunchKernelGGL(k_scan, dim3(1), dim3(1024), 0, stream, hist, cursor);
    if (use_csr) {
        hipLaunchKernelGGL(k_node, dim3((N_NODES + 63) / 64), dim3(256), 0, stream,
                           nf, wpT, bp, p1, p2);
        hipLaunchKernelGGL(k_edge, dim3(N_EDGES / 64), dim3(256), 0, stream,
                           ef, wpT, src, dst, cursor, rnk, p1, p2, msgG);
        hipLaunchKernelGGL(k_agg, dim3(N_NODES / 4), dim3(256), 0, stream,
                           msgG, cursor, hist, s1, s2, mx, mn, scal);
    } else {
        hipLaunchKernelGGL(k_copy_cursor, dim3((N_NODES + 255) / 256), dim3(256), 0, stream,
                           cursor, curs2);
        hipLaunchKernelGGL(k_scatter_fb, dim3((N_EDGES + 255) / 256), dim3(256), 0, stream,
                           dst, curs2, perm);
        hipLaunchKernelGGL(k_pretrans, dim3(N_EDGES / 64), dim3(256), 0, stream,
                           nf, ef, wpT, bp, src, dst, perm, s1, s2, mx, mn);
        hipLaunchKernelGGL(k_finalize, dim3((unsigned)((ND + 255) / 256)), dim3(256), 0, stream,
                           s1, s2, mx, mn, hist, scal);
    }
    hipLaunchKernelGGL(k_post, dim3((N_NODES + 63) / 64), dim3(256), 0, stream,
                       nf, s1, mx, mn, s2, scal, w1T, b1, w2T, b2, out);
}

// Round 19
// 509.424 us; speedup vs baseline: 2.5295x; 1.0053x over previous
//
#include <hip/hip_runtime.h>
#include <math.h>

#define N_NODES 50000
#define N_EDGES 800000
#define D 128
#define AVG_D_LOG 2.833213344056216f  /* log(17.0) */
#define EPS 1e-5f

typedef __attribute__((ext_vector_type(8))) short bf16x8;
typedef __attribute__((ext_vector_type(4))) float f32x4;

__device__ __forceinline__ unsigned short f2bf(float x) {
    unsigned u = __float_as_uint(x);
    u += 0x7fffu + ((u >> 16) & 1u);
    return (unsigned short)(u >> 16);
}
__device__ __forceinline__ unsigned pk2bf(float a, float b) {
    return (unsigned)f2bf(a) | ((unsigned)f2bf(b) << 16);
}
__device__ __forceinline__ float bf2f(unsigned short u) {
    return __uint_as_float(((unsigned)u) << 16);
}

// ---------------- init (fallback only) ----------------
__global__ void k_init(int* hist, float* s1, float* s2, float* mx, float* mn) {
    size_t stride = (size_t)gridDim.x * blockDim.x;
    size_t i0 = (size_t)blockIdx.x * blockDim.x + threadIdx.x;
    const size_t ND4 = (size_t)N_NODES * D / 4;
    float4 z4 = {0.f, 0.f, 0.f, 0.f};
    int4 inf4 = {0x7f800000, 0x7f800000, 0x7f800000, 0x7f800000};
    for (size_t t = i0; t < ND4; t += stride) {
        ((float4*)s1)[t] = z4; ((float4*)s2)[t] = z4; ((float4*)mx)[t] = z4;
        ((int4*)mn)[t] = inf4;
    }
    for (size_t t = i0; t < N_NODES; t += stride) hist[t] = 0;
}

// ---------------- fused prep: 3 weight transposes + dst histogram + edge rank ----------
__global__ void k_prep(const float* __restrict__ wp, const float* __restrict__ w1,
                       const float* __restrict__ w2,
                       unsigned short* __restrict__ wpT, unsigned short* __restrict__ w1T,
                       unsigned short* __restrict__ w2T,
                       const int* __restrict__ dst, int* hist, int* rnk) {
    int b = blockIdx.x, t = threadIdx.x;
    if (b < 192) {
        int idx = b * 256 + t;
        int k = idx >> 7, c = idx & 127;
        wpT[(size_t)c * 384 + k] = f2bf(wp[idx]);
    } else if (b < 1024) {
        int idx = (b - 192) * 256 + t;
        int k = idx >> 7, c = idx & 127;
        w1T[(size_t)c * 1664 + k] = f2bf(w1[idx]);
    } else if (b < 1088) {
        int idx = (b - 1024) * 256 + t;
        int k = idx >> 7, c = idx & 127;
        w2T[(size_t)c * 128 + k] = f2bf(w2[idx]);
    } else {
        int e = (b - 1088) * 256 + t;
        if (e < N_EDGES) rnk[e] = atomicAdd(&hist[dst[e]], 1);
    }
}

// ---------------- parallel exclusive scan: cursor[n] = row START of node n ------------
__global__ __launch_bounds__(1024) void k_scan(const int* __restrict__ hist, int* cursor) {
    __shared__ int part[1024];
    int t = threadIdx.x;
    const int chunk = (N_NODES + 1023) / 1024;
    int lo = t * chunk;
    int hi = lo + chunk; if (hi > N_NODES) hi = N_NODES;
    int s = 0;
    for (int i = lo; i < hi; ++i) s += hist[i];
    part[t] = s;
    __syncthreads();
    for (int off = 1; off < 1024; off <<= 1) {
        int v = (t >= off) ? part[t - off] : 0;
        __syncthreads();
        part[t] += v;
        __syncthreads();
    }
    int run = (t == 0) ? 0 : part[t - 1];
    for (int i = lo; i < hi; ++i) { cursor[i] = run; run += hist[i]; }
}

// fallback only: build perm
__global__ void k_scatter_fb(const int* __restrict__ dst, int* curs2, int* perm) {
    int e = blockIdx.x * blockDim.x + threadIdx.x;
    if (e < N_EDGES) {
        int pos = atomicAdd(&curs2[dst[e]], 1);
        perm[pos] = e;
    }
}
__global__ void k_copy_cursor(const int* __restrict__ cursor, int* curs2) {
    int i = blockIdx.x * blockDim.x + threadIdx.x;
    if (i < N_NODES) curs2[i] = cursor[i];
}

// ---- 256B-row-stride MFMA macros ----
#define MM256(ACC, AOFF, BOFF) do { \
    _Pragma("unroll") \
    for (int ks = 0; ks < 4; ++ks) { \
        bf16x8 afr[2], bfr[4]; \
        int kb = ks * 64 + lg * 16; \
        _Pragma("unroll") \
        for (int cf = 0; cf < 2; ++cf) { \
            int c = w * 32 + cf * 16 + lr; \
            afr[cf] = *(const bf16x8*)(smem + (AOFF) + c * 256 + (kb ^ ((c & 7) << 4))); \
        } \
        _Pragma("unroll") \
        for (int eb = 0; eb < 4; ++eb) { \
            int e = eb * 16 + lr; \
            bfr[eb] = *(const bf16x8*)(smem + (BOFF) + e * 256 + (kb ^ ((e & 7) << 4))); \
        } \
        _Pragma("unroll") \
        for (int cf = 0; cf < 2; ++cf) \
            _Pragma("unroll") \
            for (int eb = 0; eb < 4; ++eb) \
                ACC[cf][eb] = __builtin_amdgcn_mfma_f32_16x16x32_bf16( \
                    afr[cf], bfr[eb], ACC[cf][eb], 0, 0, 0); \
    } \
} while (0)

// wide variant: 128-row B tile (8 eb fragments)
#define MMW(ACC, AOFF, BOFF) do { \
    _Pragma("unroll") \
    for (int ks = 0; ks < 4; ++ks) { \
        bf16x8 afr[2], bfr[8]; \
        int kb = ks * 64 + lg * 16; \
        _Pragma("unroll") \
        for (int cf = 0; cf < 2; ++cf) { \
            int c = w * 32 + cf * 16 + lr; \
            afr[cf] = *(const bf16x8*)(smem + (AOFF) + c * 256 + (kb ^ ((c & 7) << 4))); \
        } \
        _Pragma("unroll") \
        for (int eb = 0; eb < 8; ++eb) { \
            int e = eb * 16 + lr; \
            bfr[eb] = *(const bf16x8*)(smem + (BOFF) + e * 256 + (kb ^ ((e & 7) << 4))); \
        } \
        _Pragma("unroll") \
        for (int cf = 0; cf < 2; ++cf) \
            _Pragma("unroll") \
            for (int eb = 0; eb < 8; ++eb) \
                ACC[cf][eb] = __builtin_amdgcn_mfma_f32_16x16x32_bf16( \
                    afr[cf], bfr[eb], ACC[cf][eb], 0, 0, 0); \
    } \
} while (0)

// ---------------- k_node: P1 = nf@Ws, P2 = nf@Wd + b (bf16 out) ----------------
__global__ __launch_bounds__(256) void k_node(
    const float* __restrict__ nf, const unsigned short* __restrict__ wpT,
    const float* __restrict__ bp,
    unsigned short* __restrict__ p1, unsigned short* __restrict__ p2)
{
    __shared__ __align__(16) char smem[49152];
    __shared__ float sb[128];
    int t = threadIdx.x;
    int n0 = blockIdx.x * 64;
    if (t < 128) sb[t] = bp[t];
    int w = t >> 6, l = t & 63, lr = l & 15, lg = l >> 4;

    f32x4 acc1[2][4], acc2[2][4];
    #pragma unroll
    for (int i = 0; i < 2; ++i)
        #pragma unroll
        for (int j = 0; j < 4; ++j) { acc1[i][j] = (f32x4){0.f,0.f,0.f,0.f}; acc2[i][j] = (f32x4){0.f,0.f,0.f,0.f}; }

    #pragma unroll
    for (int p = 0; p < 8; ++p) {
        int g = t + 256 * p;
        int e = g >> 5, q = g & 31;
        int n = n0 + e;
        float4 fv = {0.f, 0.f, 0.f, 0.f};
        if (n < N_NODES) fv = *(const float4*)(nf + (size_t)n * D + q * 4);
        uint2 hv = { pk2bf(fv.x, fv.y), pk2bf(fv.z, fv.w) };
        *(uint2*)(smem + 32768 + e * 256 + ((q * 8) ^ ((e & 7) << 4))) = hv;
    }
    #pragma unroll
    for (int p = 0; p < 8; ++p) {
        int g = t + 256 * p;
        int c = g >> 4, j = g & 15;
        uint4 wv = *(const uint4*)(wpT + (size_t)c * 384 + j * 8);
        *(uint4*)(smem + c * 256 + ((j * 16) ^ ((c & 7) << 4))) = wv;
    }
    __syncthreads();
    MM256(acc1, 0, 32768);
    __syncthreads();
    #pragma unroll
    for (int p = 0; p < 8; ++p) {
        int g = t + 256 * p;
        int c = g >> 4, j = g & 15;
        uint4 wv = *(const uint4*)(wpT + (size_t)c * 384 + 128 + j * 8);
        *(uint4*)(smem + c * 256 + ((j * 16) ^ ((c & 7) << 4))) = wv;
    }
    __syncthreads();
    MM256(acc2, 0, 32768);
    __syncthreads();

    #pragma unroll
    for (int cf = 0; cf < 2; ++cf)
        #pragma unroll
        for (int eb = 0; eb < 4; ++eb) {
            int e  = eb * 16 + lr;
            int c0 = w * 32 + cf * 16 + lg * 4;
            uint2 v1 = { pk2bf(acc1[cf][eb][0], acc1[cf][eb][1]),
                         pk2bf(acc1[cf][eb][2], acc1[cf][eb][3]) };
            *(uint2*)(smem + e * 256 + ((c0 * 2) ^ ((e & 7) << 4))) = v1;
            uint2 v2 = { pk2bf(acc2[cf][eb][0] + sb[c0 + 0], acc2[cf][eb][1] + sb[c0 + 1]),
                         pk2bf(acc2[cf][eb][2] + sb[c0 + 2], acc2[cf][eb][3] + sb[c0 + 3]) };
            *(uint2*)(smem + 16384 + e * 256 + ((c0 * 2) ^ ((e & 7) << 4))) = v2;
        }
    __syncthreads();
    #pragma unroll
    for (int p = 0; p < 4; ++p) {
        int e = (t >> 4) + p * 16;
        int q = t & 15;
        int n = n0 + e;
        if (n < N_NODES) {
            int qq = q ^ (e & 7);
            uint4 v1 = *(const uint4*)(smem + e * 256 + q * 16);
            *(uint4*)(p1 + (size_t)n * D + qq * 8) = v1;
            uint4 v2 = *(const uint4*)(smem + 16384 + e * 256 + q * 16);
            *(uint4*)(p2 + (size_t)n * D + qq * 8) = v2;
        }
    }
}

// ---------------- k_edge: pos = cursor[dst] + rnk ----------------
__global__ __launch_bounds__(256) void k_edge(
    const float* __restrict__ ef, const unsigned short* __restrict__ wpT,
    const int* __restrict__ src, const int* __restrict__ dst,
    const int* __restrict__ cursor, const int* __restrict__ rnk,
    const unsigned short* __restrict__ p1, const unsigned short* __restrict__ p2,
    unsigned short* __restrict__ msgG)
{
    __shared__ __align__(16) char smem[49152];
    __shared__ int sidx[64], didx[64], ridx[64];

    int t = threadIdx.x;
    int e0 = blockIdx.x * 64;
    if (t < 64) {
        int d = dst[e0 + t];
        sidx[t] = src[e0 + t];
        didx[t] = d;
        ridx[t] = cursor[d] + rnk[e0 + t];
    }
    int w = t >> 6, l = t & 63, lr = l & 15, lg = l >> 4;

    f32x4 acc[2][4];
    #pragma unroll
    for (int i = 0; i < 2; ++i)
        #pragma unroll
        for (int j = 0; j < 4; ++j) acc[i][j] = (f32x4){0.f, 0.f, 0.f, 0.f};

    #pragma unroll
    for (int p = 0; p < 8; ++p) {
        int g = t + 256 * p;
        int c = g >> 4, j = g & 15;
        uint4 wv = *(const uint4*)(wpT + (size_t)c * 384 + 256 + j * 8);
        *(uint4*)(smem + c * 256 + ((j * 16) ^ ((c & 7) << 4))) = wv;
    }
    #pragma unroll
    for (int p = 0; p < 8; ++p) {
        int g = t + 256 * p;
        int e = g >> 5, q = g & 31;
        float4 fv = *(const float4*)(ef + (size_t)(e0 + e) * D + q * 4);
        uint2 hv = { pk2bf(fv.x, fv.y), pk2bf(fv.z, fv.w) };
        *(uint2*)(smem + 32768 + e * 256 + ((q * 8) ^ ((e & 7) << 4))) = hv;
    }
    __syncthreads();
    MM256(acc, 0, 32768);
    __syncthreads();
    #pragma unroll
    for (int p = 0; p < 4; ++p) {
        int g = t + 256 * p;
        int e = g >> 4, q = g & 15;
        uint4 v1 = *(const uint4*)(p1 + (size_t)sidx[e] * D + q * 8);
        *(uint4*)(smem + e * 256 + ((q * 16) ^ ((e & 7) << 4))) = v1;
        uint4 v2 = *(const uint4*)(p2 + (size_t)didx[e] * D + q * 8);
        *(uint4*)(smem + 16384 + e * 256 + ((q * 16) ^ ((e & 7) << 4))) = v2;
    }
    __syncthreads();
    #pragma unroll
    for (int cf = 0; cf < 2; ++cf)
        #pragma unroll
        for (int eb = 0; eb < 4; ++eb) {
            int e  = eb * 16 + lr;
            int c0 = w * 32 + cf * 16 + lg * 4;
            uint2 a1 = *(const uint2*)(smem + e * 256 + ((c0 * 2) ^ ((e & 7) << 4)));
            uint2 a2 = *(const uint2*)(smem + 16384 + e * 256 + ((c0 * 2) ^ ((e & 7) << 4)));
            float v0 = acc[cf][eb][0] + bf2f((unsigned short)(a1.x & 0xffff)) + bf2f((unsigned short)(a2.x & 0xffff));
            float v1 = acc[cf][eb][1] + bf2f((unsigned short)(a1.x >> 16))    + bf2f((unsigned short)(a2.x >> 16));
            float v2 = acc[cf][eb][2] + bf2f((unsigned short)(a1.y & 0xffff)) + bf2f((unsigned short)(a2.y & 0xffff));
            float v3 = acc[cf][eb][3] + bf2f((unsigned short)(a1.y >> 16))    + bf2f((unsigned short)(a2.y >> 16));
            uint2 mv = { pk2bf(fmaxf(v0, 0.f), fmaxf(v1, 0.f)),
                         pk2bf(fmaxf(v2, 0.f), fmaxf(v3, 0.f)) };
            *(uint2*)(smem + 32768 + e * 256 + ((c0 * 2) ^ ((e & 7) << 4))) = mv;
        }
    __syncthreads();
    #pragma unroll
    for (int p = 0; p < 4; ++p) {
        int e = (t >> 4) + p * 16;
        int q = t & 15;
        uint4 v = *(const uint4*)(smem + 32768 + e * 256 + q * 16);
        int qq = q ^ (e & 7);
        *(uint4*)(msgG + (size_t)ridx[e] * D + qq * 8) = v;
    }
}

// ---------------- k_agg: SEQUENTIAL msgG rows (dst-sorted) -> fp32 aggregates ----------
__global__ __launch_bounds__(256) void k_agg(
    const unsigned short* __restrict__ msgG,
    const int* __restrict__ cursor, const int* __restrict__ hist,
    float* __restrict__ s1, float* __restrict__ s2,
    float* __restrict__ mx, float* __restrict__ mn, float* __restrict__ scal)
{
    int t = threadIdx.x;
    int n = blockIdx.x * 4 + (t >> 6);
    int tl = t & 63;
    int deg = hist[n];
    int rs  = cursor[n];

    float sum0 = 0.f, sum1 = 0.f, sq0 = 0.f, sq1 = 0.f;
    float mx0 = -3.402823e38f, mx1 = -3.402823e38f;
    float mn0 =  3.402823e38f, mn1 =  3.402823e38f;
    const uint* mg = (const uint*)msgG;
    for (int e = 0; e < deg; ++e) {
        uint v = mg[(size_t)(rs + e) * 64 + tl];
        float a = bf2f((unsigned short)(v & 0xffff));
        float b = bf2f((unsigned short)(v >> 16));
        sum0 += a; sum1 += b; sq0 += a * a; sq1 += b * b;
        mx0 = fmaxf(mx0, a); mx1 = fmaxf(mx1, b);
        mn0 = fminf(mn0, a); mn1 = fminf(mn1, b);
    }
    float dg = (float)deg;
    float ds = fmaxf(dg, 1.f);
    bool nb = deg > 0;
    float m0 = sum0 / ds, m1 = sum1 / ds;
    float sd0 = sqrtf(fmaxf(sq0 / ds - m0 * m0, 0.f) + EPS);
    float sd1 = sqrtf(fmaxf(sq1 / ds - m1 * m1, 0.f) + EPS);
    size_t base = (size_t)n * D + tl * 2;
    *(float2*)&s1[base] = (float2){m0, m1};
    *(float2*)&s2[base] = (float2){sd0, sd1};
    *(float2*)&mx[base] = (float2){nb ? mx0 : 0.f, nb ? mx1 : 0.f};
    *(float2*)&mn[base] = (float2){nb ? mn0 : 0.f, nb ? mn1 : 0.f};
    if (tl == 0) {
        float logd = logf(dg + 1.f);
        scal[2 * n]     = logd / AVG_D_LOG;
        scal[2 * n + 1] = AVG_D_LOG / fmaxf(logd, EPS);
    }
}

// staging macros for the fallback fused pretrans
#define PFN(NC, PW0, PW1, PW2, PW3, PZ0, PZ1, PZ2, PZ3) do { \
    { int g = t;       int c = g >> 3, j = g & 7;  PW0 = *(const uint4*)(wpT + (size_t)c * 384 + (NC) * 64 + j * 8); } \
    { int g = t + 256; int c = g >> 3, j = g & 7;  PW1 = *(const uint4*)(wpT + (size_t)c * 384 + (NC) * 64 + j * 8); } \
    { int g = t + 512; int c = g >> 3, j = g & 7;  PW2 = *(const uint4*)(wpT + (size_t)c * 384 + (NC) * 64 + j * 8); } \
    { int g = t + 768; int c = g >> 3, j = g & 7;  PW3 = *(const uint4*)(wpT + (size_t)c * 384 + (NC) * 64 + j * 8); } \
    { int g = t;       int e = g >> 4, q = g & 15; PZ0 = *(const float4*)(ZROW(NC, e) + (((NC) & 1) * 64) + q * 4); } \
    { int g = t + 256; int e = g >> 4, q = g & 15; PZ1 = *(const float4*)(ZROW(NC, e) + (((NC) & 1) * 64) + q * 4); } \
    { int g = t + 512; int e = g >> 4, q = g & 15; PZ2 = *(const float4*)(ZROW(NC, e) + (((NC) & 1) * 64) + q * 4); } \
    { int g = t + 768; int e = g >> 4, q = g & 15; PZ3 = *(const float4*)(ZROW(NC, e) + (((NC) & 1) * 64) + q * 4); } \
} while (0)
#define WRN(OFF, PW0, PW1, PW2, PW3, PZ0, PZ1, PZ2, PZ3) do { \
    { int g = t;       int c = g >> 3, j = g & 7;  *(uint4*)(smem + (OFF) + c * 128 + ((j * 16) ^ ((c & 7) << 4))) = PW0; } \
    { int g = t + 256; int c = g >> 3, j = g & 7;  *(uint4*)(smem + (OFF) + c * 128 + ((j * 16) ^ ((c & 7) << 4))) = PW1; } \
    { int g = t + 512; int c = g >> 3, j = g & 7;  *(uint4*)(smem + (OFF) + c * 128 + ((j * 16) ^ ((c & 7) << 4))) = PW2; } \
    { int g = t + 768; int c = g >> 3, j = g & 7;  *(uint4*)(smem + (OFF) + c * 128 + ((j * 16) ^ ((c & 7) << 4))) = PW3; } \
    { int g = t;       int e = g >> 4, q = g & 15; uint2 hv = { pk2bf(PZ0.x, PZ0.y), pk2bf(PZ0.z, PZ0.w) }; \
      *(uint2*)(smem + (OFF) + 16384 + e * 128 + ((q * 8) ^ ((e & 7) << 4))) = hv; } \
    { int g = t + 256; int e = g >> 4, q = g & 15; uint2 hv = { pk2bf(PZ1.x, PZ1.y), pk2bf(PZ1.z, PZ1.w) }; \
      *(uint2*)(smem + (OFF) + 16384 + e * 128 + ((q * 8) ^ ((e & 7) << 4))) = hv; } \
    { int g = t + 512; int e = g >> 4, q = g & 15; uint2 hv = { pk2bf(PZ2.x, PZ2.y), pk2bf(PZ2.z, PZ2.w) }; \
      *(uint2*)(smem + (OFF) + 16384 + e * 128 + ((q * 8) ^ ((e & 7) << 4))) = hv; } \
    { int g = t + 768; int e = g >> 4, q = g & 15; uint2 hv = { pk2bf(PZ3.x, PZ3.y), pk2bf(PZ3.z, PZ3.w) }; \
      *(uint2*)(smem + (OFF) + 16384 + e * 128 + ((q * 8) ^ ((e & 7) << 4))) = hv; } \
} while (0)
#define MMO(OFF) do { \
    _Pragma("unroll") \
    for (int ks = 0; ks < 2; ++ks) { \
        bf16x8 afr[2], bfr[4]; \
        int kb = ks * 64 + lg * 16; \
        _Pragma("unroll") \
        for (int cf = 0; cf < 2; ++cf) { \
            int c = w * 32 + cf * 16 + lr; \
            afr[cf] = *(const bf16x8*)(smem + (OFF) + c * 128 + (kb ^ ((c & 7) << 4))); \
        } \
        _Pragma("unroll") \
        for (int eb = 0; eb < 4; ++eb) { \
            int e = eb * 16 + lr; \
            bfr[eb] = *(const bf16x8*)(smem + (OFF) + 16384 + e * 128 + (kb ^ ((e & 7) << 4))); \
        } \
        _Pragma("unroll") \
        for (int cf = 0; cf < 2; ++cf) \
            _Pragma("unroll") \
            for (int eb = 0; eb < 4; ++eb) \
                acc[cf][eb] = __builtin_amdgcn_mfma_f32_16x16x32_bf16( \
                    afr[cf], bfr[eb], acc[cf][eb], 0, 0, 0); \
    } \
} while (0)

// ---------------- fallback: fused pretrans (all-atomic epilogue) ----------------
__global__ __launch_bounds__(256) void k_pretrans(
    const float* __restrict__ nf, const float* __restrict__ ef,
    const unsigned short* __restrict__ wpT, const float* __restrict__ bp,
    const int* __restrict__ src, const int* __restrict__ dst,
    const int* __restrict__ perm,
    float* s1, float* s2, float* mx, float* mn)
{
    __shared__ __align__(16) char smem[24576];
    __shared__ int pidx[64], sidx[64], didx[64];
    __shared__ int seg_start[65], seg_dst[64];
    __shared__ int nseg_s;
    __shared__ float sb[128];

    int t = threadIdx.x;
    int e0 = blockIdx.x * 64;
    if (t < 64) {
        int pe = perm[e0 + t];
        pidx[t] = pe; sidx[t] = src[pe]; didx[t] = dst[pe];
    }
    if (t < 128) sb[t] = bp[t];
    __syncthreads();

    int w  = t >> 6;
    int l  = t & 63;
    int lr = l & 15;
    int lg = l >> 4;

    f32x4 acc[2][4];
    #pragma unroll
    for (int i = 0; i < 2; ++i)
        #pragma unroll
        for (int j = 0; j < 4; ++j) acc[i][j] = (f32x4){0.f, 0.f, 0.f, 0.f};

    uint4  pw0, pw1, pw2, pw3;
    float4 pz0, pz1, pz2, pz3;

#define ZROW(NC, e) ((NC) < 2 ? nf + (size_t)sidx[e] * D : \
                     (NC) < 4 ? nf + (size_t)didx[e] * D : \
                                ef + (size_t)pidx[e] * D)
    PFN(0, pw0, pw1, pw2, pw3, pz0, pz1, pz2, pz3);
    WRN(0, pw0, pw1, pw2, pw3, pz0, pz1, pz2, pz3); PFN(1, pw0, pw1, pw2, pw3, pz0, pz1, pz2, pz3); __syncthreads(); MMO(0); __syncthreads();
    WRN(0, pw0, pw1, pw2, pw3, pz0, pz1, pz2, pz3); PFN(2, pw0, pw1, pw2, pw3, pz0, pz1, pz2, pz3); __syncthreads(); MMO(0); __syncthreads();
    WRN(0, pw0, pw1, pw2, pw3, pz0, pz1, pz2, pz3); PFN(3, pw0, pw1, pw2, pw3, pz0, pz1, pz2, pz3); __syncthreads(); MMO(0); __syncthreads();
    WRN(0, pw0, pw1, pw2, pw3, pz0, pz1, pz2, pz3); PFN(4, pw0, pw1, pw2, pw3, pz0, pz1, pz2, pz3); __syncthreads(); MMO(0); __syncthreads();
    WRN(0, pw0, pw1, pw2, pw3, pz0, pz1, pz2, pz3); PFN(5, pw0, pw1, pw2, pw3, pz0, pz1, pz2, pz3); __syncthreads(); MMO(0); __syncthreads();
    WRN(0, pw0, pw1, pw2, pw3, pz0, pz1, pz2, pz3);                                                 __syncthreads(); MMO(0); __syncthreads();
#undef ZROW

    #pragma unroll
    for (int cf = 0; cf < 2; ++cf)
        #pragma unroll
        for (int eb = 0; eb < 4; ++eb) {
            int e  = eb * 16 + lr;
            int c0 = w * 32 + cf * 16 + lg * 4;
            float v0 = fmaxf(acc[cf][eb][0] + sb[c0 + 0], 0.f);
            float v1 = fmaxf(acc[cf][eb][1] + sb[c0 + 1], 0.f);
            float v2 = fmaxf(acc[cf][eb][2] + sb[c0 + 2], 0.f);
            float v3 = fmaxf(acc[cf][eb][3] + sb[c0 + 3], 0.f);
            uint2 mv = { pk2bf(v0, v1), pk2bf(v2, v3) };
            *(uint2*)(smem + e * 256 + ((c0 * 2) ^ ((e & 7) << 4))) = mv;
        }
    if (t == 0) {
        int ns = 0;
        for (int e = 0; e < 64; ++e) {
            if (e == 0 || didx[e] != didx[e - 1]) { seg_dst[ns] = didx[e]; seg_start[ns] = e; ++ns; }
        }
        seg_start[ns] = 64; nseg_s = ns;
    }
    __syncthreads();
    int nseg = nseg_s;
    for (int idx = t; idx < nseg * D; idx += 256) {
        int sg = idx >> 7, c = idx & 127;
        int eb2 = seg_start[sg], ee = seg_start[sg + 1];
        float s = 0.f, q = 0.f, vmax = 0.f, vmin = __int_as_float(0x7f800000);
        for (int e = eb2; e < ee; ++e) {
            float v = bf2f(*(const unsigned short*)(smem + e * 256 + ((c * 2) ^ ((e & 7) << 4))));
            s += v; q += v * v;
            vmax = fmaxf(vmax, v); vmin = fminf(vmin, v);
        }
        size_t base = (size_t)seg_dst[sg] * D + c;
        atomicAdd(&s1[base], s);
        atomicAdd(&s2[base], q);
        atomicMax((int*)&mx[base], __float_as_int(vmax));
        atomicMin((int*)&mn[base], __float_as_int(vmin));
    }
}

#undef PFN
#undef WRN
#undef MMO

// ---------------- fallback: finalize in place + scalers ----------------
__global__ void k_finalize(float* s1, float* s2, float* mx, float* mn,
                           const int* __restrict__ hist, float* scal) {
    size_t idx = (size_t)blockIdx.x * blockDim.x + threadIdx.x;
    if (idx >= (size_t)N_NODES * D) return;
    int n = (int)(idx >> 7);
    int c = (int)(idx & 127);
    float dg = (float)hist[n];
    float ds = fmaxf(dg, 1.f);
    float m  = s1[idx] / ds;
    float var = fmaxf(s2[idx] / ds - m * m, 0.f);
    float sd  = sqrtf(var + EPS);
    bool nb = dg > 0.f;
    s1[idx] = m;
    mx[idx] = nb ? mx[idx] : 0.f;
    mn[idx] = nb ? mn[idx] : 0.f;
    s2[idx] = sd;
    if (c == 0) {
        float logd = logf(dg + 1.f);
        scal[2 * n]     = logd / AVG_D_LOG;
        scal[2 * n + 1] = AVG_D_LOG / fmaxf(logd, EPS);
    }
}

// ---------------- fused posttrans (128-node tile): out = relu(h@W1+b1)@W2 + b2 + nf ----
// Halves weight-staging traffic (391 blocks vs 782) and barriers-per-node.
__global__ __launch_bounds__(256, 2) void k_post(
    const float* __restrict__ nf,
    const float* __restrict__ amean, const float* __restrict__ amax,
    const float* __restrict__ amin,  const float* __restrict__ astd,
    const float* __restrict__ scal,
    const unsigned short* __restrict__ w1T, const float* __restrict__ b1,
    const unsigned short* __restrict__ w2T, const float* __restrict__ b2,
    float* __restrict__ out)
{
    __shared__ __align__(16) char smem[65536]; // W 32KB @0, B 32KB @32768
    __shared__ float samp[128], satt[128], sb1[128], sb2[128];

    int t = threadIdx.x;
    int n0 = blockIdx.x * 128;
    if (t < 128) {
        int n = n0 + t;
        samp[t] = (n < N_NODES) ? scal[2 * n] : 0.f;
        satt[t] = (n < N_NODES) ? scal[2 * n + 1] : 0.f;
        sb1[t] = b1[t]; sb2[t] = b2[t];
    }
    __syncthreads();

    int w  = t >> 6, l = t & 63, lr = l & 15, lg = l >> 4;
    f32x4 acc[2][8];
    #pragma unroll
    for (int i = 0; i < 2; ++i)
        #pragma unroll
        for (int j = 0; j < 8; ++j) acc[i][j] = (f32x4){0.f, 0.f, 0.f, 0.f};

    for (int chunk = 0; chunk < 13; ++chunk) {
        #pragma unroll
        for (int p = 0; p < 8; ++p) {
            int g = t + 256 * p;
            int c = g >> 4, j = g & 15;
            uint4 wv = *(const uint4*)(w1T + (size_t)c * 1664 + chunk * 128 + j * 8);
            *(uint4*)(smem + c * 256 + ((j * 16) ^ ((c & 7) << 4))) = wv;
        }
        const float* base;
        int r;
        if (chunk == 0) { base = nf; r = 0; }
        else {
            int b = (chunk - 1) & 3;
            r = (chunk - 1) >> 2;
            base = (b == 0) ? amean : (b == 1) ? amax : (b == 2) ? amin : astd;
        }
        #pragma unroll
        for (int p = 0; p < 16; ++p) {
            int g = t + 256 * p;
            int e = g >> 5, q = g & 31;
            int n = n0 + e;
            float4 fv = {0.f, 0.f, 0.f, 0.f};
            if (n < N_NODES) {
                fv = *(const float4*)(base + (size_t)n * D + q * 4);
                if (r == 1) { float sc = samp[e]; fv.x *= sc; fv.y *= sc; fv.z *= sc; fv.w *= sc; }
                else if (r == 2) { float sc = satt[e]; fv.x *= sc; fv.y *= sc; fv.z *= sc; fv.w *= sc; }
            }
            uint2 hv = { pk2bf(fv.x, fv.y), pk2bf(fv.z, fv.w) };
            *(uint2*)(smem + 32768 + e * 256 + ((q * 8) ^ ((e & 7) << 4))) = hv;
        }
        __syncthreads();
        MMW(acc, 0, 32768);
        __syncthreads();
    }

    // h1 = relu(acc + b1) -> LDS B-layout @32768
    #pragma unroll
    for (int cf = 0; cf < 2; ++cf)
        #pragma unroll
        for (int eb = 0; eb < 8; ++eb) {
            int e  = eb * 16 + lr;
            int c0 = w * 32 + cf * 16 + lg * 4;
            float v0 = fmaxf(acc[cf][eb][0] + sb1[c0 + 0], 0.f);
            float v1 = fmaxf(acc[cf][eb][1] + sb1[c0 + 1], 0.f);
            float v2 = fmaxf(acc[cf][eb][2] + sb1[c0 + 2], 0.f);
            float v3 = fmaxf(acc[cf][eb][3] + sb1[c0 + 3], 0.f);
            uint2 hv = { pk2bf(v0, v1), pk2bf(v2, v3) };
            *(uint2*)(smem + 32768 + e * 256 + ((c0 * 2) ^ ((e & 7) << 4))) = hv;
        }
    #pragma unroll
    for (int p = 0; p < 8; ++p) {
        int g = t + 256 * p;
        int c = g >> 4, j = g & 15;
        uint4 wv = *(const uint4*)(w2T + (size_t)c * 128 + j * 8);
        *(uint4*)(smem + c * 256 + ((j * 16) ^ ((c & 7) << 4))) = wv;
    }
    __syncthreads();

    f32x4 acc2[2][8];
    #pragma unroll
    for (int i = 0; i < 2; ++i)
        #pragma unroll
        for (int j = 0; j < 8; ++j) acc2[i][j] = (f32x4){0.f, 0.f, 0.f, 0.f};
    MMW(acc2, 0, 32768);

    #pragma unroll
    for (int cf = 0; cf < 2; ++cf)
        #pragma unroll
        for (int eb = 0; eb < 8; ++eb) {
            int n = n0 + eb * 16 + lr;
            if (n < N_NODES) {
                int c0 = w * 32 + cf * 16 + lg * 4;
                float4 rv = *(const float4*)(nf + (size_t)n * D + c0);
                float4 ov = { acc2[cf][eb][0] + sb2[c0 + 0] + rv.x,
                              acc2[cf][eb][1] + sb2[c0 + 1] + rv.y,
                              acc2[cf][eb][2] + sb2[c0 + 2] + rv.z,
                              acc2[cf][eb][3] + sb2[c0 + 3] + rv.w };
                *(float4*)(out + (size_t)n * D + c0) = ov;
            }
        }
}

extern "C" void kernel_launch(void* const* d_in, const int* in_sizes, int n_in,
                              void* d_out, int out_size, void* d_ws, size_t ws_size,
                              hipStream_t stream) {
    const float* nf = (const float*)d_in[0];
    const float* ef = (const float*)d_in[1];
    const float* wp = (const float*)d_in[2];
    const float* bp = (const float*)d_in[3];
    const float* w1 = (const float*)d_in[4];
    const float* b1 = (const float*)d_in[5];
    const float* w2 = (const float*)d_in[6];
    const float* b2 = (const float*)d_in[7];
    const int* src  = (const int*)d_in[8];
    const int* dst  = (const int*)d_in[9];
    float* out = (float*)d_out;

    const size_t ND = (size_t)N_NODES * D;       // 6.4M
    const size_t MSG_SH = (size_t)N_EDGES * D;   // 102.4M ushorts
    char* wsb = (char*)d_ws;
    int*   hist   = (int*)wsb;                                   // 50048
    int*   cursor = hist + 50048;                                // 50048 (row starts)
    int*   curs2  = cursor + 50048;                              // 50048 (fallback scratch)
    int*   perm   = curs2 + 50048;                               // 800000 (fallback only)
    int*   rnk    = perm + N_EDGES;                              // 800000
    unsigned short* wpT = (unsigned short*)(rnk + N_EDGES);      // 49152
    unsigned short* w1T = wpT + 49152;                           // 212992
    unsigned short* w2T = w1T + 212992;                          // 16384
    unsigned short* tail = w2T + 16384;

    // CSR layout
    unsigned short* p1   = tail;                 // ND bf16
    unsigned short* p2   = p1 + ND;              // ND bf16
    unsigned short* msgG = p2 + ND;              // MSG_SH bf16 (dst-sorted)
    float* s1   = (float*)(msgG + MSG_SH);
    float* s2   = s1 + ND;
    float* mx   = s2 + ND;
    float* mn   = mx + ND;
    float* scal = mn + ND;
    size_t need_csr = (size_t)((char*)(scal + 100096) - wsb);

    bool use_csr = ws_size >= need_csr;
    if (!use_csr) {
        s1   = (float*)tail;
        s2   = s1 + ND;
        mx   = s2 + ND;
        mn   = mx + ND;
        scal = mn + ND;
    }

    if (use_csr) {
        hipMemsetAsync(hist, 0, N_NODES * sizeof(int), stream);
    } else {
        hipLaunchKernelGGL(k_init, dim3(2048), dim3(256), 0, stream, hist, s1, s2, mx, mn);
    }
    hipLaunchKernelGGL(k_prep, dim3(1088 + (N_EDGES + 255) / 256), dim3(256), 0, stream,
                       wp, w1, w2, wpT, w1T, w2T, dst, hist, rnk);
    hipLaunchKernelGGL(k_scan, dim3(1), dim3(1024), 0, stream, hist, cursor);
    if (use_csr) {
        hipLaunchKernelGGL(k_node, dim3((N_NODES + 63) / 64), dim3(256), 0, stream,
                           nf, wpT, bp, p1, p2);
        hipLaunchKernelGGL(k_edge, dim3(N_EDGES / 64), dim3(256), 0, stream,
                           ef, wpT, src, dst, cursor, rnk, p1, p2, msgG);
        hipLaunchKernelGGL(k_agg, dim3(N_NODES / 4), dim3(256), 0, stream,
                           msgG, cursor, hist, s1, s2, mx, mn, scal);
    } else {
        hipLaunchKernelGGL(k_copy_cursor, dim3((N_NODES + 255) / 256), dim3(256), 0, stream,
                           cursor, curs2);
        hipLaunchKernelGGL(k_scatter_fb, dim3((N_EDGES + 255) / 256), dim3(256), 0, stream,
                           dst, curs2, perm);
        hipLaunchKernelGGL(k_pretrans, dim3(N_EDGES / 64), dim3(256), 0, stream,
                           nf, ef, wpT, bp, src, dst, perm, s1, s2, mx, mn);
        hipLaunchKernelGGL(k_finalize, dim3((unsigned)((ND + 255) / 256)), dim3(256), 0, stream,
                           s1, s2, mx, mn, hist, scal);
    }
    hipLaunchKernelGGL(k_post, dim3((N_NODES + 127) / 128), dim3(256), 0, stream,
                       nf, s1, mx, mn, s2, scal, w1T, b1, w2T, b2, out);
}